// Round 10
// baseline (306.134 us; speedup 1.0000x reference)
//
#include <hip/hip_runtime.h>
#include <math.h>

// RegionProposalNetwork on MI355X (gfx950).
// Round 22: resubmission of round 21 (bench infra failed twice; audit found
// no deadlock/race: uniform barrier counts, correct vmcnt(2) slot discipline,
// monotonic filtered atomicMax, LDS <= 91KB < 160KB).
//  - iou1: filtered conditional LDS atomicMax replaces 6-deep shfl_xor chain.
//  - conv_body: 3 A-slots, depth-2 DMA prefetch, raw s_barrier + counted
//    s_waitcnt vmcnt(2) (never 0 mid-loop).
//  - setup: vectorized bf16 image conversion (stride 1616, left pad 11).

#define CAP 4096

typedef __attribute__((ext_vector_type(8))) short bf16x8;
typedef __attribute__((ext_vector_type(4))) float f32x4;

// async 16B/lane global->LDS DMA (dest = wave-uniform base + lane*16)
__device__ __forceinline__ void dma16(const void* g, void* l) {
    __builtin_amdgcn_global_load_lds((const __attribute__((address_space(1))) void*)g,
                                     (__attribute__((address_space(3))) void*)l, 16, 0, 0);
}

// ---------------- workspace layout (float offsets) ----------------
#define OFF_F1T     0          // 5,171,328 f = 402*402*64 bf16 (conv1 out, padded transposed)
#define OFF_FMT     5171328    // 1,331,712 f = 102*102*256 bf16 (fm, padded transposed)
#define OFF_CPART   6503040    //   720,000 (4*18*10000)
#define OFF_RPART   7223040    // 1,440,000 (4*36*10000)
#define OFF_WA1     8663040    //     6,144 f = 64*192 bf16 (conv1 weights, K'=192)
#define OFF_W9_2    8672448    //    73,728 f = 18 units x 16KB   [(cc*2+kcl)][ocT][lane][8]
#define OFF_W9_3    8746176    //   294,912 f = 72 units x 16KB   (cc = kk*4+ch)
#define OFF_WTC     9041088    //     4,608 [256][18] f32
#define OFF_WTG     9045696    //     9,216 [256][36] f32
#define OFF_AARG    9054912    //    90,000 (int)
#define OFF_NEGM    9144912    //     2,816 f = 1408 uint64 (neg label bitmask)
#define OFF_POSM    9147728    //     2,816 f = 1408 uint64 (pos label bitmask)
#define OFF_GTMAX   9150544    //    64 uint + counter (pad 80)
#define OFF_CANDS   9150688    //    4,096
#define OFF_CANDI   9154784    //    4,096 (int)
#define OFF_IMGB    9158880    // 3,897,792 f = 3*1608*1616 bf16 (padded bf16 image, left pad 11)

__device__ __forceinline__ unsigned short f2bf(float f) {   // RNE f32->bf16
    unsigned int u = __float_as_uint(f);
    u += 0x7fffu + ((u >> 16) & 1u);
    return (unsigned short)(u >> 16);
}

// ---------------- selection-path exact math ----------------
__device__ __forceinline__ void anchor_box(int i, float& x0, float& y0,
                                           float& x1, float& y1, float& area) {
#pragma clang fp contract(off)
    const float sizes[3]  = {128.f, 256.f, 512.f};
    const float ratios[3] = {0.5f, 1.f, 2.f};
    int a = i % 9;
    int q = i / 9;
    int iy = q % 100;
    int ix = q / 100;
    int s = a / 3, r = a % 3;
    float sq = sqrtf(ratios[r]);
    float w = sizes[s] * sq;
    float h = sizes[s] / sq;
    float cx = ((float)ix + 0.5f) * 16.0f;
    float cy = ((float)iy + 0.5f) * 16.0f;
    x0 = cx - w * 0.5f;
    y0 = cy - h * 0.5f;
    x1 = x0 + w;
    y1 = y0 + h;
    area = (x1 - x0) * (y1 - y0);
}

__device__ __forceinline__ float iou_one(float ax0, float ay0, float ax1, float ay1, float aa,
                                         float bx0, float by0, float bx1, float by1, float ab) {
#pragma clang fp contract(off)
    float ltx = fmaxf(ax0, bx0), lty = fmaxf(ay0, by0);
    float rbx = fminf(ax1, bx1), rby = fminf(ay1, by1);
    float iw = fmaxf(rbx - ltx, 0.0f);
    float ih = fmaxf(rby - lty, 0.0f);
    float inter = iw * ih;
    return inter / ((aa + ab) - inter);
}

// ---------------- merged setup: counters, borders, weights, bf16 image ----------------
__global__ __launch_bounds__(256) void setup_kernel(const float* __restrict__ wc, float* __restrict__ wtc,
                                                    const float* __restrict__ wg, float* __restrict__ wtg,
                                                    const float* __restrict__ w1, unsigned short* __restrict__ wa1,
                                                    const float* __restrict__ w2, unsigned short* __restrict__ w9_2,
                                                    const float* __restrict__ wr, unsigned short* __restrict__ w9_3,
                                                    unsigned int* __restrict__ f1t_u, unsigned int* __restrict__ fmt_u,
                                                    unsigned int* __restrict__ gtmax,
                                                    const float* __restrict__ img, unsigned short* __restrict__ imgb) {
    int i = blockIdx.x * 256 + threadIdx.x;
    if (i < 65) { gtmax[i] = 0u; return; }
    i -= 65;
    if (i < 103040) {   // zero pad borders of f1t / fmt
        if (i < 51328) {
            int p = i >> 5, part = i & 31;
            int x, y;
            if (p < 804) { y = (p < 402) ? 0 : 401; x = p % 402; }
            else { int j = p - 804; x = (j < 400) ? 0 : 401; y = 1 + (j % 400); }
            f1t_u[(y * 402 + x) * 32 + part] = 0u;
        } else {
            int i2 = i - 51328;
            int p = i2 >> 7, part = i2 & 127;
            int x, y;
            if (p < 204) { y = (p < 102) ? 0 : 101; x = p % 102; }
            else { int j = p - 204; x = (j < 100) ? 0 : 101; y = 1 + (j % 100); }
            fmt_u[(y * 102 + x) * 128 + part] = 0u;
        }
        return;
    }
    i -= 103040;
    if (i < 4608) { int c = i / 256, k = i - c * 256; wtc[k * 18 + c] = wc[i]; return; }
    i -= 4608;
    if (i < 9216) { int c = i / 256, k = i - c * 256; wtg[k * 36 + c] = wg[i]; return; }
    i -= 9216;
    if (i < 12288) {    // conv1 weights -> [oc][k'], k' = (ky*3+ic)*8 + kx, K'=192
        int oc = i / 192, k = i - oc * 192;
        int q = k >> 3, kx = k & 7;
        int ky = q / 3, ic = q - (q / 3) * 3;
        wa1[i] = (q < 21 && kx < 7) ? f2bf(w1[oc * 147 + ic * 49 + ky * 7 + kx])
                                    : (unsigned short)0;
        return;
    }
    i -= 12288;
    if (i < 147456) {   // conv2 weights: unit=(cc*2+kcl) of 8192 shorts: [ocT][lane][8]
        int unit = i >> 13;
        int rem = i & 8191;
        int ocT = rem >> 9;
        int rem2 = rem & 511;
        int lane = rem2 >> 3;
        int e = rem2 & 7;
        int cc = unit >> 1, kcl = unit & 1;
        int oc = ocT * 16 + (lane & 15);
        int ic = kcl * 32 + (lane >> 4) * 8 + e;
        w9_2[i] = f2bf(w2[(oc * 64 + ic) * 9 + cc]);
        return;
    }
    i -= 147456;
    if (i < 589824) {   // conv3 weights: unit=(cc*2+kcl), cc = kk*4+chv
        int unit = i >> 13;
        int rem = i & 8191;
        int ocT = rem >> 9;
        int rem2 = rem & 511;
        int lane = rem2 >> 3;
        int e = rem2 & 7;
        int cc = unit >> 1, kcl = unit & 1;
        int kk = cc >> 2, chv = cc & 3;
        int oc = ocT * 16 + (lane & 15);
        int icl = kcl * 32 + (lane >> 4) * 8 + e;
        w9_3[i] = f2bf(wr[(oc * 256 + chv * 64 + icl) * 9 + kk]);
        return;
    }
    i -= 589824;
    if (i < 974448) {   // bf16 image, vectorized: 3 ch x 1608 rows x 202 chunks of 8
        int ic = i / 324816;
        int rem = i - ic * 324816;
        int row = rem / 202;            // padded row 0..1607
        int k = rem - row * 202;        // chunk 0..201
        int y = row - 3;                // img y
        bool yok = (y >= 0) && (y < 1600);
        int yc = min(max(y, 0), 1599);
        const float* srow = img + ((size_t)(ic * 1600 + yc)) * 1600;
        unsigned int d[4];
#pragma unroll
        for (int e2 = 0; e2 < 4; e2++) {
            int x0 = k * 8 + 2 * e2 - 11;
            int x1 = x0 + 1;
            bool ok0 = yok && (x0 >= 0) && (x0 < 1600);
            bool ok1 = yok && (x1 >= 0) && (x1 < 1600);
            float f0 = srow[min(max(x0, 0), 1599)];
            float f1 = srow[min(max(x1, 0), 1599)];
            unsigned int lo = ok0 ? (unsigned int)f2bf(f0) : 0u;
            unsigned int hi = ok1 ? (unsigned int)f2bf(f1) : 0u;
            d[e2] = lo | (hi << 16);
        }
        *(uint4*)(imgb + ((size_t)(ic * 1608 + row)) * 1616 + k * 8) =
            make_uint4(d[0], d[1], d[2], d[3]);
    }
}

// ---------------- iou pass bodies (fused into conv launches) ----------------
__device__ __forceinline__ void iou1_body(int bid, int t, const float* __restrict__ gt,
                                          int* __restrict__ aarg, unsigned int* __restrict__ gtmax) {
    __shared__ float sg1[64][4];
    __shared__ float sarea1[64];
    __shared__ unsigned int smax1[64];
    if (t < 64) {
#pragma clang fp contract(off)
        float b0 = gt[t * 4 + 0], b1 = gt[t * 4 + 1];
        float b2 = gt[t * 4 + 2], b3 = gt[t * 4 + 3];
        sg1[t][0] = b0; sg1[t][1] = b1; sg1[t][2] = b2; sg1[t][3] = b3;
        sarea1[t] = (b2 - b0) * (b3 - b1);
        smax1[t] = 0u;
    }
    __syncthreads();
    int i = bid * 256 + t;
    int iq = min(i, 89999);
    float x0, y0, x1, y1, aa;
    anchor_box(iq, x0, y0, x1, y1, aa);
    float best = -1.f;
    int bestj = 0;
    for (int j = 0; j < 64; j++) {
        float v = iou_one(x0, y0, x1, y1, aa, sg1[j][0], sg1[j][1], sg1[j][2], sg1[j][3], sarea1[j]);
        if (v > best) { best = v; bestj = j; }
        // filtered exact max: snapshot read + monotonic atomicMax (no miss possible)
        if (v > __uint_as_float(smax1[j])) atomicMax(&smax1[j], __float_as_uint(v));
    }
    if (i < 90000) aarg[i] = bestj;
    __syncthreads();
    if (t < 64) atomicMax(&gtmax[t], smax1[t]);
}

__device__ __forceinline__ void iou2_body(int bid, int t, const float* __restrict__ gt,
                                          const unsigned int* __restrict__ gtmax,
                                          unsigned long long* __restrict__ negmask,
                                          unsigned long long* __restrict__ posmask,
                                          float* __restrict__ cand_s, int* __restrict__ cand_i,
                                          unsigned int* __restrict__ cnt) {
    __shared__ float sg2[64][4];
    __shared__ float sarea2[64];
    __shared__ float sgm2[64];
    if (t < 64) {
#pragma clang fp contract(off)
        float b0 = gt[t * 4 + 0], b1 = gt[t * 4 + 1];
        float b2 = gt[t * 4 + 2], b3 = gt[t * 4 + 3];
        sg2[t][0] = b0; sg2[t][1] = b1; sg2[t][2] = b2; sg2[t][3] = b3;
        sarea2[t] = (b2 - b0) * (b3 - b1);
        sgm2[t] = __uint_as_float(gtmax[t]);
    }
    __syncthreads();
    int i = bid * 512 + t;
    if (i >= 90000) return;
    float x0, y0, x1, y1, aa;
    anchor_box(i, x0, y0, x1, y1, aa);
    float best = -1.f;
    bool isbest = false;
    for (int j = 0; j < 64; j++) {
        float v = iou_one(x0, y0, x1, y1, aa, sg2[j][0], sg2[j][1], sg2[j][2], sg2[j][3], sarea2[j]);
        if (v > best) best = v;
        if (v == sgm2[j]) isbest = true;   // exact equality, identical f32 code path as pass 1
    }
    float label = -1.f;
    if (best < 0.2f) label = 0.f;
    if (isbest) label = 1.f;
    if (best > 0.7f) label = 1.f;
    unsigned long long negb = __ballot(label == 0.f);
    unsigned long long posb = __ballot(label == 1.f);
    if ((t & 63) == 0) { negmask[i >> 6] = negb; posmask[i >> 6] = posb; }
    if (label == 1.f) {
        unsigned int p = atomicAdd(cnt, 1u);
        if (p < CAP) { cand_s[p] = best; cand_i[p] = i; }
    }
}

// ---------------- conv1 body via MFMA: 3->64, 7x7, s4, p3 ----------------
// bf16 image pre-padded (pad 11 left / stride 1616 / 3 top rows zero).
// 13 DMA ops land win[24][264] directly; rows 21-23 + slack from zero rows.
__device__ __forceinline__ void conv1_body(int bx, int oy, int t,
                                           const unsigned short* __restrict__ imgb,
                                           const unsigned short* __restrict__ wA,
                                           const float* __restrict__ bias,
                                           unsigned short* __restrict__ f1t) {
    __shared__ __align__(16) unsigned char smem[13312];   // 13 ops x 1024B
    unsigned short* win = (unsigned short*)smem;          // [24][264] = 12,672 B
    unsigned short* tileT = (unsigned short*)smem;        // [64][72] alias after MFMA
    int wave = t >> 6, lane = t & 63;
    int quad = lane >> 4, l16 = lane & 15;
    int ox0 = bx * 64;
    int col0 = ox0 * 4 + 8;             // img x = ox0*4-3 at win col 0; mult of 8 -> 16B aligned
    int gy0 = 4 * oy - 3;

    // 13 DMA ops, 3-4 per wave; chunk q -> win row q/33, col chunk q%33
    for (int o = wave; o < 13; o += 4) {
        int q = o * 64 + lane;
        int r = q / 33;
        int c = q - r * 33;
        int rc = min(r, 20);
        int ky = rc / 3, ic = rc - (rc / 3) * 3;
        int yp = gy0 + ky + 3;          // in [0,1605]
        size_t offm = ((size_t)(ic * 1608 + yp)) * 1616 + col0 + c * 8;
        size_t offz = (size_t)(q - 693) * 8;   // rows 0-2 of ch0 are all zero
        dma16(imgb + ((r < 21) ? offm : offz), (char*)smem + o * 1024);
    }
    // A fragments (L2-resident weights)
    bf16x8 afr[6];
    {
        const bf16x8* ap = (const bf16x8*)(wA + (wave * 16 + l16) * 192 + quad * 8);
#pragma unroll
        for (int c = 0; c < 6; c++) afr[c] = ap[c * 4];
    }
    __syncthreads();    // drains DMA for all waves

    f32x4 acc[4];
#pragma unroll
    for (int j = 0; j < 4; j++) acc[j] = (f32x4){0.f, 0.f, 0.f, 0.f};
#pragma unroll
    for (int ch = 0; ch < 6; ch++) {
        const unsigned short* wrow = win + (ch * 4 + quad) * 264;
#pragma unroll
        for (int j = 0; j < 4; j++) {
            int px = j * 16 + l16;
            const unsigned long long* bp = (const unsigned long long*)(wrow + 4 * px); // 8B-aligned
            union { unsigned long long u[2]; bf16x8 v; } uu;
            uu.u[0] = bp[0];
            uu.u[1] = bp[1];
            acc[j] = __builtin_amdgcn_mfma_f32_16x16x32_bf16(afr[ch], uu.v, acc[j], 0, 0, 0);
        }
    }
    __syncthreads();    // win dead; tileT aliases it
#pragma unroll
    for (int reg = 0; reg < 4; reg++) {
        int oc = wave * 16 + quad * 4 + reg;
        float bv = bias[oc];
#pragma unroll
        for (int j = 0; j < 4; j++) {
            int px = j * 16 + l16;
            tileT[px * 72 + oc] = f2bf(fmaxf(acc[j][reg] + bv, 0.f));
        }
    }
    __syncthreads();
    int px = t >> 2, part = t & 3;
    int ox = ox0 + px;
    if (ox < 400) {
        int row = (oy + 1) * 402 + ox + 1;
        uint4 v0 = *(const uint4*)(tileT + px * 72 + part * 16);
        uint4 v1 = *(const uint4*)(tileT + px * 72 + part * 16 + 8);
        *(uint4*)(f1t + row * 64 + part * 16) = v0;
        *(uint4*)(f1t + row * 64 + part * 16 + 8) = v1;
    }
}

// conv1 + iou_pass1 fused launch
__global__ __launch_bounds__(256, 4) void conv1_iou1(const unsigned short* __restrict__ imgb,
                                                     const unsigned short* __restrict__ wA,
                                                     const float* __restrict__ bias,
                                                     unsigned short* __restrict__ f1t,
                                                     const float* __restrict__ gt,
                                                     int* __restrict__ aarg,
                                                     unsigned int* __restrict__ gtmax) {
    int t = threadIdx.x;
    if (blockIdx.x < 7) {
        conv1_body(blockIdx.x, blockIdx.y, t, imgb, wA, bias, f1t);
    } else {
        int bid = blockIdx.y;
        if (bid < 352) iou1_body(bid, t, gt, aarg, gtmax);
    }
}

// ---------------- implicit-GEMM conv body: pipelined LDS A, 25px tiles ------
// 8 waves = 4 ocT-groups (ow) x 2 pixel-halves (ph). B DMA'd once. A DMA'd
// per (cc,kcl) 16KB unit into 3 slots, depth-2 prefetch; per-step sync is
// raw s_barrier + counted s_waitcnt vmcnt(2) (prefetch stays in flight across
// barriers).
template<int ICC, int RS, int S, bool WRT, bool HEAD>
__device__ __forceinline__ void conv_body(int xs, int y, int t,
                                          const unsigned short* __restrict__ Bt,
                                          const unsigned short* __restrict__ A9,
                                          const float* __restrict__ bias,
                                          float* __restrict__ outF,
                                          unsigned short* __restrict__ outT,
                                          const float* __restrict__ wtc,
                                          const float* __restrict__ wtg,
                                          float* __restrict__ cpart,
                                          float* __restrict__ rpart) {
    constexpr int NC = ICC / 64;            // 1 | 4
    constexpr int HC = S * 24 + 3;          // cols: conv2=99, conv3=27
    constexpr int CHW = ICC / 8;            // 16B chunks per col: 8 | 32
    constexpr int TOT = 3 * HC * CHW;       // 2376 | 2592
    constexpr int BOPS = (TOT + 63) / 64;   // 38 | 41
    constexpr int BB = BOPS * 1024;         // 38912 | 41984
    constexpr int NS = (NC == 1) ? 18 : 72; // (cc,kcl) units
    __shared__ __align__(16) unsigned char smem[BB + 49152];   // B + 3 A-slots
    unsigned short* blds = (unsigned short*)smem;
    float* hlds = (float*)(smem + BB);      // [256][26] f32 (HEAD only, reuses A slots)

    int wave = t >> 6, lane = t & 63;
    int ow = wave & 3, ph = wave >> 2;
    int quad = lane >> 4, l16 = lane & 15;
    int oc0 = ow * 64;
    int pl = ph * 16 + l16;                 // output pixel 0..31
    int pxe = min(pl, 24);
    int swp = pxe & 7;                      // conv2 read swizzle

    // ---- B staging: linear dest chunk q; source chunk XOR-swizzled
    for (int o = wave; o < BOPS; o += 8) {
        int q = min(o * 64 + lane, TOT - 1);
        int row = q / CHW;
        int e = q - row * CHW;
        int ky = row / HC;
        int c = row - ky * HC;
        int sz = (S == 4) ? (e ^ ((c >> 2) & 7)) : (e ^ (row & 7));
        dma16(Bt + ((size_t)(S * y + ky) * RS + S * xs * 25 + c) * ICC + sz * 8,
              (char*)smem + o * 1024);
    }
    // ---- A units 0,1 -> slots 0,1 (2 ops/wave each)
    {
        char* s0 = (char*)smem + BB;
        dma16(A9 + (size_t)(wave * 64 + lane) * 8, s0 + wave * 1024);
        dma16(A9 + (size_t)((wave + 8) * 64 + lane) * 8, s0 + (wave + 8) * 1024);
        if (NS > 1) {
            char* s1 = (char*)smem + BB + 16384;
            const unsigned short* a1 = A9 + 8192;
            dma16(a1 + (size_t)(wave * 64 + lane) * 8, s1 + wave * 1024);
            dma16(a1 + (size_t)((wave + 8) * 64 + lane) * 8, s1 + (wave + 8) * 1024);
        }
    }

    f32x4 acc[4];
#pragma unroll
    for (int mt = 0; mt < 4; mt++) acc[mt] = (f32x4){0.f, 0.f, 0.f, 0.f};
    __syncthreads();    // full drain: B + A0 + A1 ready

    for (int u = 0; u < NS; u++) {
        // compute unit u from slot u%3
        const unsigned short* ab = (const unsigned short*)(smem + BB + (u % 3) * 16384);
        int cc = u >> 1, kcl = u & 1;
        int pass = cc / NC, ch = cc - pass * NC;
        int ky = pass / 3, kx = pass - (pass / 3) * 3;
        int row = ky * HC + S * pxe + kx;
        int ck = kcl * 4 + quad;
        int chunk = (S == 4) ? (ck ^ swp) : ((ch * 8 + ck) ^ (row & 7));
        bf16x8 bf = *(const bf16x8*)(blds + row * ICC + chunk * 8);
#pragma unroll
        for (int mt = 0; mt < 4; mt++) {
            bf16x8 af = *(const bf16x8*)(ab + ((ow * 4 + mt) * 64 + lane) * 8);
            acc[mt] = __builtin_amdgcn_mfma_f32_16x16x32_bf16(af, bf, acc[mt], 0, 0, 0);
        }
        // depth-2 prefetch: issue unit u+2 into slot (u+2)%3 (readers of that
        // slot finished at barrier u-1)
        if (u + 2 < NS) {
            char* dst = (char*)smem + BB + ((u + 2) % 3) * 16384;
            const unsigned short* src = A9 + (size_t)(u + 2) * 8192;
            dma16(src + (size_t)(wave * 64 + lane) * 8, dst + wave * 1024);
            dma16(src + (size_t)((wave + 8) * 64 + lane) * 8, dst + (wave + 8) * 1024);
        }
        if (u + 1 < NS) {
            if (u + 2 < NS) asm volatile("s_waitcnt vmcnt(2)" ::: "memory");
            else            asm volatile("s_waitcnt vmcnt(0)" ::: "memory");
            __builtin_amdgcn_s_barrier();
            __builtin_amdgcn_sched_barrier(0);
        }
    }

    if (HEAD) __syncthreads();   // all waves done reading A slots before hlds reuse

    // ---- epilogue: bias + relu; write out (or hlds for HEAD)
#pragma unroll
    for (int mt = 0; mt < 4; mt++) {
#pragma unroll
        for (int reg = 0; reg < 4; reg++) {
            int oc = oc0 + mt * 16 + quad * 4 + reg;
            float bv = bias[oc];
            if (pl < 25) {
                float v = fmaxf(acc[mt][reg] + bv, 0.f);
                if (HEAD) {
                    hlds[oc * 26 + pl] = v;
                } else {
                    int p = y * 100 + xs * 25 + pl;
                    outF[oc * 10000 + p] = v;
                    if (WRT) {
                        int r = (y + 1) * 102 + xs * 25 + pl + 1;
                        outT[r * 256 + oc] = f2bf(v);
                    }
                }
            }
        }
    }
    if (HEAD) {
        __syncthreads();
        int base = y * 100 + xs * 25;
        // 5400 items: ch(4) x j(54) x p(25); 64-MAC dot each, ic ascending
        for (int it = t; it < 5400; it += 512) {
            int ch = it / 1350;
            int r = it - ch * 1350;
            int j = r / 25;
            int p = r - j * 25;
            int jc = (j < 18) ? j : (j - 18);
            const float* wt = (j < 18) ? (wtc + jc) : (wtg + jc);
            int stride = (j < 18) ? 18 : 36;
            int ic0 = ch * 64;
            float acc2 = 0.f;
#pragma unroll 8
            for (int ic = 0; ic < 64; ic++)
                acc2 += hlds[(ic0 + ic) * 26 + p] * wt[(ic0 + ic) * stride];
            float* dst = (j < 18) ? (cpart + (ch * 18 + jc) * 10000)
                                  : (rpart + (ch * 36 + jc) * 10000);
            dst[base + p] = acc2;
        }
    }
}

// conv2 + iou_pass2 fused launch
__global__ __launch_bounds__(512) void conv2_iou2(const unsigned short* __restrict__ Bt,
                                                  const unsigned short* __restrict__ A9,
                                                  const float* __restrict__ bias,
                                                  float* __restrict__ outF,
                                                  unsigned short* __restrict__ outT,
                                                  const float* __restrict__ gt,
                                                  const unsigned int* __restrict__ gtmax,
                                                  unsigned long long* __restrict__ negmask,
                                                  unsigned long long* __restrict__ posmask,
                                                  float* __restrict__ cand_s,
                                                  int* __restrict__ cand_i,
                                                  unsigned int* __restrict__ cnt) {
    int t = threadIdx.x;
    if (blockIdx.x < 4) {
        conv_body<64, 402, 4, true, false>(blockIdx.x, blockIdx.y, t, Bt, A9, bias,
                                           outF, outT, nullptr, nullptr, nullptr, nullptr);
    } else {
        int bid = (blockIdx.x - 4) * 100 + blockIdx.y;
        if (bid < 176) iou2_body(bid, t, gt, gtmax, negmask, posmask, cand_s, cand_i, cnt);
    }
}

// conv3 + heads fused launch
__global__ __launch_bounds__(512) void conv3_head(const unsigned short* __restrict__ Bt,
                                                  const unsigned short* __restrict__ A9,
                                                  const float* __restrict__ bias,
                                                  const float* __restrict__ wtc,
                                                  const float* __restrict__ wtg,
                                                  float* __restrict__ cpart,
                                                  float* __restrict__ rpart) {
    conv_body<256, 102, 1, false, true>(blockIdx.x, blockIdx.y, threadIdx.x, Bt, A9, bias,
                                        nullptr, nullptr, wtc, wtg, cpart, rpart);
}

// ---------------- single-wave helpers ----------------
__device__ __forceinline__ unsigned long long shflx64(unsigned long long v, int m) {
    int lo = __shfl_xor((int)(unsigned)(v & 0xFFFFFFFFull), m);
    int hi = __shfl_xor((int)(unsigned)(v >> 32), m);
    return ((unsigned long long)(unsigned)hi << 32) | (unsigned)lo;
}

// first-32 set bits (ascending index) of the 90000-bit mask; single wave, no barriers
__device__ int wave_first32(const unsigned long long* __restrict__ mask,
                            bool invert, int* __restrict__ outIdx, int lane) {
    const int NW = 1407;            // ceil(90000/64)
    const int WPT = 22;             // 64*22 = 1408 >= 1407
    unsigned long long mw[WPT];
    int cnt = 0;
#pragma unroll
    for (int u = 0; u < WPT; u++) {
        int w = lane * WPT + u;
        unsigned long long m = 0ull;
        if (w < NW) {
            m = mask[w];
            if (invert) m = ~m;
            if (w == NW - 1) m &= 0xFFFFull;    // anchors 89984..89999 only
        }
        mw[u] = m;
        cnt += __builtin_popcountll(m);
    }
    int inc = cnt;                  // inclusive prefix over lanes via shuffles
#pragma unroll
    for (int off = 1; off < 64; off <<= 1) {
        int v = __shfl_up(inc, off);
        if (lane >= off) inc += v;
    }
    int total = __shfl(inc, 63);
    int pref = inc - cnt;           // exclusive prefix
    if (pref < 32) {
#pragma unroll
        for (int u = 0; u < WPT; u++) {
            unsigned long long m = mw[u];
            int wbase = (lane * WPT + u) * 64;
            while (m && pref < 32) {
                int b = __builtin_ctzll(m);
                outIdx[pref++] = wbase + b;
                m &= m - 1;
            }
        }
    }
    return total;
}

// ---------------- tail: top-k selection + proposals + losses (one wave) ----------------
__global__ __launch_bounds__(64) void tail_kernel(const unsigned long long* __restrict__ negmask,
                                                  const unsigned long long* __restrict__ posmask,
                                                  const float* __restrict__ cand_s,
                                                  const int* __restrict__ cand_i,
                                                  const unsigned int* __restrict__ cnt,
                                                  const float* __restrict__ cpart,
                                                  const float* __restrict__ rpart,
                                                  const float* __restrict__ bcls,
                                                  const float* __restrict__ breg,
                                                  const int* __restrict__ aarg,
                                                  const float* __restrict__ gt,
                                                  const int* __restrict__ gtc,
                                                  float* __restrict__ out) {
    __shared__ unsigned long long keys[CAP + 32];
    __shared__ int sfill[32];
    __shared__ int spidx[32];
    __shared__ int snidx[32];
    int lane = threadIdx.x;

    // ---- build sort keys: (monotonic(score) << 32) | ~index  => max = (score desc, idx asc)
    int ncand = min((int)*cnt, CAP);
    for (int c = lane; c < ncand; c += 64) {
        unsigned u = __float_as_uint(cand_s[c]);
        u ^= (u & 0x80000000u) ? 0xFFFFFFFFu : 0x80000000u;
        keys[c] = ((unsigned long long)u << 32) | (0xFFFFFFFFu - (unsigned)cand_i[c]);
    }
    int ntot = ncand;
    if (ncand < 32) {               // jax top_k tie fill: first label!=1 anchors at value -1
        int tot = wave_first32(posmask, true, sfill, lane);
        int nfill = min(tot, 32);
        unsigned um1 = __float_as_uint(-1.0f) ^ 0xFFFFFFFFu;
        for (int k2 = lane; k2 < nfill; k2 += 64)
            keys[ncand + k2] = ((unsigned long long)um1 << 32) | (0xFFFFFFFFu - (unsigned)sfill[k2]);
        ntot += nfill;
    }

    // ---- 32 rounds of wave argmax; lane owns slots c == lane (mod 64)
    unsigned long long lk = 0ull; int ls = -1;
    for (int c = lane; c < ntot; c += 64) {
        unsigned long long k = keys[c];
        if (k > lk) { lk = k; ls = c; }
    }
    for (int s = 0; s < 32; s++) {
        unsigned long long mk = lk;
#pragma unroll
        for (int off = 1; off < 64; off <<= 1) {
            unsigned long long o = shflx64(mk, off);
            if (o > mk) mk = o;
        }
        if (lk == mk && mk != 0ull) {   // unique winner (keys embed unique indices)
            spidx[s] = (int)(0xFFFFFFFFu - (unsigned)(mk & 0xFFFFFFFFull));
            keys[ls] = 0ull;
            lk = 0ull; ls = -1;
            for (int c = lane; c < ntot; c += 64) {
                unsigned long long k = keys[c];
                if (k > lk) { lk = k; ls = c; }
            }
        }
    }

    // ---- negatives: first 32 label==0 anchors (ascending index)
    int totn = wave_first32(negmask, false, snidx, lane);
    if (lane == 0) {
        int nf = min(totn, 32);
        for (int s = nf; s < 32; s++) snidx[s] = s;   // degenerate fallback
    }

    // ---- finalize (same math as before) ----
    {
#pragma clang fp contract(off)
        const int PROP_OFF = 1 + 2560000;
        int t = lane;
        int n = (t < 32) ? spidx[t] : snidx[t - 32];
        int a = n % 9;
        int q = n / 9;
        int iy = q % 100;
        int ix = q / 100;
        int p = iy * 100 + ix;

        float l0 = bcls[a * 2 + 0], l1 = bcls[a * 2 + 1];
        for (int c = 0; c < 4; c++) {
            l0 += cpart[(c * 18 + a * 2 + 0) * 10000 + p];
            l1 += cpart[(c * 18 + a * 2 + 1) * 10000 + p];
        }
        float m = fmaxf(l0, l1);
        float lse = m + logf(expf(l0 - m) + expf(l1 - m));
        float logp = ((t < 32) ? l1 : l0) - lse;
        float cls_sum = logp;
#pragma unroll
        for (int off = 32; off > 0; off >>= 1) cls_sum += __shfl_down(cls_sum, off);

        float reg_sum = 0.f;
        if (t < 32) {
            float offv[4];
#pragma unroll
            for (int k = 0; k < 4; k++) {
                float v = breg[a * 4 + k];
                for (int c = 0; c < 4; c++) v += rpart[(c * 36 + a * 4 + k) * 10000 + p];
                offv[k] = v;
            }
            float x0, y0, x1, y1, aa;
            anchor_box(n, x0, y0, x1, y1, aa);
            float w = x1 - x0, h = y1 - y0;
            float cx = x0 + 0.5f * w, cy = y0 + 0.5f * h;
            float ncx = cx + offv[0] * w, ncy = cy + offv[1] * h;
            float nw = w * expf(offv[2]), nh = h * expf(offv[3]);
            out[PROP_OFF + t * 4 + 0] = ncx - nw * 0.5f;
            out[PROP_OFF + t * 4 + 1] = ncy - nh * 0.5f;
            out[PROP_OFF + t * 4 + 2] = ncx + nw * 0.5f;
            out[PROP_OFF + t * 4 + 3] = ncy + nh * 0.5f;

            int j = aarg[n];
            float g0 = gt[j * 4 + 0], g1 = gt[j * 4 + 1];
            float g2 = gt[j * 4 + 2], g3 = gt[j * 4 + 3];
            float gw = g2 - g0, gh = g3 - g1;
            float gcx = g0 + 0.5f * gw, gcy = g1 + 0.5f * gh;
            float tg[4];
            tg[0] = (gcx - cx) / w;
            tg[1] = (gcy - cy) / h;
            tg[2] = logf(gw / w);
            tg[3] = logf(gh / h);
#pragma unroll
            for (int k = 0; k < 4; k++) {
                float d = tg[k] - offv[k];
                float ad = fabsf(d);
                reg_sum += (ad < 1.f) ? 0.5f * d * d : ad - 0.5f;
            }
            out[PROP_OFF + 128 + t] = (float)n;
            out[PROP_OFF + 160 + t] = (float)gtc[j];
        }
#pragma unroll
        for (int off = 32; off > 0; off >>= 1) reg_sum += __shfl_down(reg_sum, off);
        if (t == 0) {
            float cls_loss = -(cls_sum / 64.f);
            float reg_loss = reg_sum / 128.f;
            out[0] = cls_loss + 5.f * reg_loss;
        }
    }
}

// ---------------- launch ----------------
extern "C" void kernel_launch(void* const* d_in, const int* in_sizes, int n_in,
                              void* d_out, int out_size, void* d_ws, size_t ws_size,
                              hipStream_t stream) {
    const float* img = (const float*)d_in[0];
    const float* gt  = (const float*)d_in[1];
    const int*   gtc = (const int*)d_in[2];
    const float* w1  = (const float*)d_in[3];
    const float* b1  = (const float*)d_in[4];
    const float* w2  = (const float*)d_in[5];
    const float* b2  = (const float*)d_in[6];
    const float* wr  = (const float*)d_in[7];
    const float* br  = (const float*)d_in[8];
    const float* wc  = (const float*)d_in[9];
    const float* bc  = (const float*)d_in[10];
    const float* wg  = (const float*)d_in[11];
    const float* bg  = (const float*)d_in[12];
    float* out = (float*)d_out;
    float* ws = (float*)d_ws;

    unsigned short* f1t  = (unsigned short*)(ws + OFF_F1T);
    unsigned short* fmt  = (unsigned short*)(ws + OFF_FMT);
    unsigned short* wa1  = (unsigned short*)(ws + OFF_WA1);
    unsigned short* w9_2 = (unsigned short*)(ws + OFF_W9_2);
    unsigned short* w9_3 = (unsigned short*)(ws + OFF_W9_3);
    unsigned short* imgb = (unsigned short*)(ws + OFF_IMGB);
    float* cpart = ws + OFF_CPART;
    float* rpart = ws + OFF_RPART;
    float* wtc   = ws + OFF_WTC;
    float* wtg   = ws + OFF_WTG;
    int*   aarg  = (int*)(ws + OFF_AARG);
    unsigned long long* negm = (unsigned long long*)(ws + OFF_NEGM);
    unsigned long long* posm = (unsigned long long*)(ws + OFF_POSM);
    unsigned int* gtmax = (unsigned int*)(ws + OFF_GTMAX);
    unsigned int* cnt   = gtmax + 64;
    float* cands = ws + OFF_CANDS;
    int*   candi = (int*)(ws + OFF_CANDI);
    float* fm    = out + 1;   // fm lives directly in the output buffer (f32)

    setup_kernel<<<dim3(7192), dim3(256), 0, stream>>>(wc, wtc, wg, wtg, w1, wa1,
                                                       w2, w9_2, wr, w9_3,
                                                       (unsigned int*)f1t, (unsigned int*)fmt, gtmax,
                                                       img, imgb);

    conv1_iou1<<<dim3(8, 400), dim3(256), 0, stream>>>(imgb, wa1, b1, f1t, gt, aarg, gtmax);
    conv2_iou2<<<dim3(6, 100), dim3(512), 0, stream>>>(f1t, w9_2, b2, fm, fmt,
                                                       gt, gtmax, negm, posm, cands, candi, cnt);
    conv3_head<<<dim3(4, 100), dim3(512), 0, stream>>>(fmt, w9_3, br, wtc, wtg, cpart, rpart);
    tail_kernel<<<dim3(1), dim3(64), 0, stream>>>(negm, posm, cands, candi, cnt,
                                                  cpart, rpart, bc, bg, aarg, gt, gtc, out);
}

// Round 11
// 270.482 us; speedup vs baseline: 1.1318x; 1.1318x over previous
//
#include <hip/hip_runtime.h>
#include <math.h>

// RegionProposalNetwork on MI355X (gfx950).
// Round 23: compose the empirically-best pieces.
//  - conv_body: REVERT to R17 structure (best total, 270us): kg K-split,
//    25px tiles, VGPR afA/afB double-buffered direct-global A, kg-reduce in
//    dead B buffer, launch_bounds(512,4). R19-R22 conv_gemm rewrites (13px,
//    LDS-A, 72-step counted-vmcnt pipeline) all regressed: 1 blk/CU + 4 MFMA
//    per barrier can't hide ~400cy/step of barrier+vmcnt latency.
//  - KEEP: DMA B-staging linear+XOR (R19+, absmax-verified), DMA conv1 via
//    pre-padded bf16 image (R19), filtered-atomicMax iou1 (R21), vectorized
//    setup (R21).

#define CAP 4096

typedef __attribute__((ext_vector_type(8))) short bf16x8;
typedef __attribute__((ext_vector_type(4))) float f32x4;

// async 16B/lane global->LDS DMA (dest = wave-uniform base + lane*16)
__device__ __forceinline__ void dma16(const void* g, void* l) {
    __builtin_amdgcn_global_load_lds((const __attribute__((address_space(1))) void*)g,
                                     (__attribute__((address_space(3))) void*)l, 16, 0, 0);
}

// ---------------- workspace layout (float offsets) ----------------
#define OFF_F1T     0          // 5,171,328 f = 402*402*64 bf16 (conv1 out, padded transposed)
#define OFF_FMT     5171328    // 1,331,712 f = 102*102*256 bf16 (fm, padded transposed)
#define OFF_CPART   6503040    //   720,000 (4*18*10000)
#define OFF_RPART   7223040    // 1,440,000 (4*36*10000)
#define OFF_WA1     8663040    //     6,144 f = 64*192 bf16 (conv1 weights, K'=192)
#define OFF_W9_2    8672448    //    73,728 f = bf16, [(cc*16+ocT)*2+kcl][lane][8]
#define OFF_W9_3    8746176    //   294,912 f = bf16, same chunking; cc = kk*4+chv
#define OFF_WTC     9041088    //     4,608 [256][18] f32
#define OFF_WTG     9045696    //     9,216 [256][36] f32
#define OFF_AARG    9054912    //    90,000 (int)
#define OFF_NEGM    9144912    //     2,816 f = 1408 uint64 (neg label bitmask)
#define OFF_POSM    9147728    //     2,816 f = 1408 uint64 (pos label bitmask)
#define OFF_GTMAX   9150544    //    64 uint + counter (pad 80)
#define OFF_CANDS   9150688    //    4,096
#define OFF_CANDI   9154784    //    4,096 (int)
#define OFF_IMGB    9158880    // 3,897,792 f = 3*1608*1616 bf16 (padded bf16 image, left pad 11)

__device__ __forceinline__ unsigned short f2bf(float f) {   // RNE f32->bf16
    unsigned int u = __float_as_uint(f);
    u += 0x7fffu + ((u >> 16) & 1u);
    return (unsigned short)(u >> 16);
}

// ---------------- selection-path exact math ----------------
__device__ __forceinline__ void anchor_box(int i, float& x0, float& y0,
                                           float& x1, float& y1, float& area) {
#pragma clang fp contract(off)
    const float sizes[3]  = {128.f, 256.f, 512.f};
    const float ratios[3] = {0.5f, 1.f, 2.f};
    int a = i % 9;
    int q = i / 9;
    int iy = q % 100;
    int ix = q / 100;
    int s = a / 3, r = a % 3;
    float sq = sqrtf(ratios[r]);
    float w = sizes[s] * sq;
    float h = sizes[s] / sq;
    float cx = ((float)ix + 0.5f) * 16.0f;
    float cy = ((float)iy + 0.5f) * 16.0f;
    x0 = cx - w * 0.5f;
    y0 = cy - h * 0.5f;
    x1 = x0 + w;
    y1 = y0 + h;
    area = (x1 - x0) * (y1 - y0);
}

__device__ __forceinline__ float iou_one(float ax0, float ay0, float ax1, float ay1, float aa,
                                         float bx0, float by0, float bx1, float by1, float ab) {
#pragma clang fp contract(off)
    float ltx = fmaxf(ax0, bx0), lty = fmaxf(ay0, by0);
    float rbx = fminf(ax1, bx1), rby = fminf(ay1, by1);
    float iw = fmaxf(rbx - ltx, 0.0f);
    float ih = fmaxf(rby - lty, 0.0f);
    float inter = iw * ih;
    return inter / ((aa + ab) - inter);
}

// ---------------- merged setup: counters, borders, weights, bf16 image ----------------
__global__ __launch_bounds__(256) void setup_kernel(const float* __restrict__ wc, float* __restrict__ wtc,
                                                    const float* __restrict__ wg, float* __restrict__ wtg,
                                                    const float* __restrict__ w1, unsigned short* __restrict__ wa1,
                                                    const float* __restrict__ w2, unsigned short* __restrict__ w9_2,
                                                    const float* __restrict__ wr, unsigned short* __restrict__ w9_3,
                                                    unsigned int* __restrict__ f1t_u, unsigned int* __restrict__ fmt_u,
                                                    unsigned int* __restrict__ gtmax,
                                                    const float* __restrict__ img, unsigned short* __restrict__ imgb) {
    int i = blockIdx.x * 256 + threadIdx.x;
    if (i < 65) { gtmax[i] = 0u; return; }
    i -= 65;
    if (i < 103040) {   // zero pad borders of f1t / fmt
        if (i < 51328) {
            int p = i >> 5, part = i & 31;
            int x, y;
            if (p < 804) { y = (p < 402) ? 0 : 401; x = p % 402; }
            else { int j = p - 804; x = (j < 400) ? 0 : 401; y = 1 + (j % 400); }
            f1t_u[(y * 402 + x) * 32 + part] = 0u;
        } else {
            int i2 = i - 51328;
            int p = i2 >> 7, part = i2 & 127;
            int x, y;
            if (p < 204) { y = (p < 102) ? 0 : 101; x = p % 102; }
            else { int j = p - 204; x = (j < 100) ? 0 : 101; y = 1 + (j % 100); }
            fmt_u[(y * 102 + x) * 128 + part] = 0u;
        }
        return;
    }
    i -= 103040;
    if (i < 4608) { int c = i / 256, k = i - c * 256; wtc[k * 18 + c] = wc[i]; return; }
    i -= 4608;
    if (i < 9216) { int c = i / 256, k = i - c * 256; wtg[k * 36 + c] = wg[i]; return; }
    i -= 9216;
    if (i < 12288) {    // conv1 weights -> [oc][k'], k' = (ky*3+ic)*8 + kx, K'=192
        int oc = i / 192, k = i - oc * 192;
        int q = k >> 3, kx = k & 7;
        int ky = q / 3, ic = q - (q / 3) * 3;
        wa1[i] = (q < 21 && kx < 7) ? f2bf(w1[oc * 147 + ic * 49 + ky * 7 + kx])
                                    : (unsigned short)0;
        return;
    }
    i -= 12288;
    if (i < 147456) {   // conv2 weights, chunked: i = ((cc*16+ocT)*2+kcl)*512 + lane*8 + e
        int cc = i >> 14;
        int rem = i & 16383;
        int ocT = rem >> 10;
        int rem2 = rem & 1023;
        int kcl = rem2 >> 9;
        int lane = (rem2 & 511) >> 3;
        int e = rem2 & 7;
        int oc = ocT * 16 + (lane & 15);
        int ic = kcl * 32 + (lane >> 4) * 8 + e;
        w9_2[i] = f2bf(w2[(oc * 64 + ic) * 9 + cc]);
        return;
    }
    i -= 147456;
    if (i < 589824) {   // conv3 weights, chunked; cc = kk*4+chv
        int cc = i >> 14;
        int rem = i & 16383;
        int ocT = rem >> 10;
        int rem2 = rem & 1023;
        int kcl = rem2 >> 9;
        int lane = (rem2 & 511) >> 3;
        int e = rem2 & 7;
        int kk = cc >> 2, chv = cc & 3;
        int oc = ocT * 16 + (lane & 15);
        int icl = kcl * 32 + (lane >> 4) * 8 + e;
        w9_3[i] = f2bf(wr[(oc * 256 + chv * 64 + icl) * 9 + kk]);
        return;
    }
    i -= 589824;
    if (i < 974448) {   // bf16 image, vectorized: 3 ch x 1608 rows x 202 chunks of 8
        int ic = i / 324816;
        int rem = i - ic * 324816;
        int row = rem / 202;            // padded row 0..1607
        int k = rem - row * 202;        // chunk 0..201
        int y = row - 3;                // img y
        bool yok = (y >= 0) && (y < 1600);
        int yc = min(max(y, 0), 1599);
        const float* srow = img + ((size_t)(ic * 1600 + yc)) * 1600;
        unsigned int d[4];
#pragma unroll
        for (int e2 = 0; e2 < 4; e2++) {
            int x0 = k * 8 + 2 * e2 - 11;
            int x1 = x0 + 1;
            bool ok0 = yok && (x0 >= 0) && (x0 < 1600);
            bool ok1 = yok && (x1 >= 0) && (x1 < 1600);
            float f0 = srow[min(max(x0, 0), 1599)];
            float f1 = srow[min(max(x1, 0), 1599)];
            unsigned int lo = ok0 ? (unsigned int)f2bf(f0) : 0u;
            unsigned int hi = ok1 ? (unsigned int)f2bf(f1) : 0u;
            d[e2] = lo | (hi << 16);
        }
        *(uint4*)(imgb + ((size_t)(ic * 1608 + row)) * 1616 + k * 8) =
            make_uint4(d[0], d[1], d[2], d[3]);
    }
}

// ---------------- iou pass bodies (fused into conv launches) ----------------
__device__ __forceinline__ void iou1_body(int bid, int t, const float* __restrict__ gt,
                                          int* __restrict__ aarg, unsigned int* __restrict__ gtmax) {
    __shared__ float sg1[64][4];
    __shared__ float sarea1[64];
    __shared__ unsigned int smax1[64];
    if (t < 64) {
#pragma clang fp contract(off)
        float b0 = gt[t * 4 + 0], b1 = gt[t * 4 + 1];
        float b2 = gt[t * 4 + 2], b3 = gt[t * 4 + 3];
        sg1[t][0] = b0; sg1[t][1] = b1; sg1[t][2] = b2; sg1[t][3] = b3;
        sarea1[t] = (b2 - b0) * (b3 - b1);
        smax1[t] = 0u;
    }
    __syncthreads();
    int i = bid * 256 + t;
    int iq = min(i, 89999);
    float x0, y0, x1, y1, aa;
    anchor_box(iq, x0, y0, x1, y1, aa);
    float best = -1.f;
    int bestj = 0;
    for (int j = 0; j < 64; j++) {
        float v = iou_one(x0, y0, x1, y1, aa, sg1[j][0], sg1[j][1], sg1[j][2], sg1[j][3], sarea1[j]);
        if (v > best) { best = v; bestj = j; }
        // filtered exact max: snapshot read + monotonic atomicMax (no miss possible)
        if (v > __uint_as_float(smax1[j])) atomicMax(&smax1[j], __float_as_uint(v));
    }
    if (i < 90000) aarg[i] = bestj;
    __syncthreads();
    if (t < 64) atomicMax(&gtmax[t], smax1[t]);
}

__device__ __forceinline__ void iou2_body(int bid, int t, const float* __restrict__ gt,
                                          const unsigned int* __restrict__ gtmax,
                                          unsigned long long* __restrict__ negmask,
                                          unsigned long long* __restrict__ posmask,
                                          float* __restrict__ cand_s, int* __restrict__ cand_i,
                                          unsigned int* __restrict__ cnt) {
    __shared__ float sg2[64][4];
    __shared__ float sarea2[64];
    __shared__ float sgm2[64];
    if (t < 64) {
#pragma clang fp contract(off)
        float b0 = gt[t * 4 + 0], b1 = gt[t * 4 + 1];
        float b2 = gt[t * 4 + 2], b3 = gt[t * 4 + 3];
        sg2[t][0] = b0; sg2[t][1] = b1; sg2[t][2] = b2; sg2[t][3] = b3;
        sarea2[t] = (b2 - b0) * (b3 - b1);
        sgm2[t] = __uint_as_float(gtmax[t]);
    }
    __syncthreads();
    int i = bid * 512 + t;
    if (i >= 90000) return;
    float x0, y0, x1, y1, aa;
    anchor_box(i, x0, y0, x1, y1, aa);
    float best = -1.f;
    bool isbest = false;
    for (int j = 0; j < 64; j++) {
        float v = iou_one(x0, y0, x1, y1, aa, sg2[j][0], sg2[j][1], sg2[j][2], sg2[j][3], sarea2[j]);
        if (v > best) best = v;
        if (v == sgm2[j]) isbest = true;   // exact equality, identical f32 code path as pass 1
    }
    float label = -1.f;
    if (best < 0.2f) label = 0.f;
    if (isbest) label = 1.f;
    if (best > 0.7f) label = 1.f;
    unsigned long long negb = __ballot(label == 0.f);
    unsigned long long posb = __ballot(label == 1.f);
    if ((t & 63) == 0) { negmask[i >> 6] = negb; posmask[i >> 6] = posb; }
    if (label == 1.f) {
        unsigned int p = atomicAdd(cnt, 1u);
        if (p < CAP) { cand_s[p] = best; cand_i[p] = i; }
    }
}

// ---------------- conv1 body via MFMA: 3->64, 7x7, s4, p3 ----------------
// bf16 image pre-padded (pad 11 left / stride 1616 / 3 top rows zero).
// 13 DMA ops land win[24][264] directly; rows 21-23 + slack from zero rows.
__device__ __forceinline__ void conv1_body(int bx, int oy, int t,
                                           const unsigned short* __restrict__ imgb,
                                           const unsigned short* __restrict__ wA,
                                           const float* __restrict__ bias,
                                           unsigned short* __restrict__ f1t) {
    __shared__ __align__(16) unsigned char smem[13312];   // 13 ops x 1024B
    unsigned short* win = (unsigned short*)smem;          // [24][264] = 12,672 B
    unsigned short* tileT = (unsigned short*)smem;        // [64][72] alias after MFMA
    int wave = t >> 6, lane = t & 63;
    int quad = lane >> 4, l16 = lane & 15;
    int ox0 = bx * 64;
    int col0 = ox0 * 4 + 8;             // img x = ox0*4-3 at win col 0; mult of 8 -> 16B aligned
    int gy0 = 4 * oy - 3;

    // 13 DMA ops, 3-4 per wave; chunk q -> win row q/33, col chunk q%33
    for (int o = wave; o < 13; o += 4) {
        int q = o * 64 + lane;
        int r = q / 33;
        int c = q - r * 33;
        int rc = min(r, 20);
        int ky = rc / 3, ic = rc - (rc / 3) * 3;
        int yp = gy0 + ky + 3;          // in [0,1605]
        size_t offm = ((size_t)(ic * 1608 + yp)) * 1616 + col0 + c * 8;
        size_t offz = (size_t)(q - 693) * 8;   // rows 0-2 of ch0 are all zero
        dma16(imgb + ((r < 21) ? offm : offz), (char*)smem + o * 1024);
    }
    // A fragments (L2-resident weights)
    bf16x8 afr[6];
    {
        const bf16x8* ap = (const bf16x8*)(wA + (wave * 16 + l16) * 192 + quad * 8);
#pragma unroll
        for (int c = 0; c < 6; c++) afr[c] = ap[c * 4];
    }
    __syncthreads();    // drains DMA for all waves

    f32x4 acc[4];
#pragma unroll
    for (int j = 0; j < 4; j++) acc[j] = (f32x4){0.f, 0.f, 0.f, 0.f};
#pragma unroll
    for (int ch = 0; ch < 6; ch++) {
        const unsigned short* wrow = win + (ch * 4 + quad) * 264;
#pragma unroll
        for (int j = 0; j < 4; j++) {
            int px = j * 16 + l16;
            const unsigned long long* bp = (const unsigned long long*)(wrow + 4 * px); // 8B-aligned
            union { unsigned long long u[2]; bf16x8 v; } uu;
            uu.u[0] = bp[0];
            uu.u[1] = bp[1];
            acc[j] = __builtin_amdgcn_mfma_f32_16x16x32_bf16(afr[ch], uu.v, acc[j], 0, 0, 0);
        }
    }
    __syncthreads();    // win dead; tileT aliases it
#pragma unroll
    for (int reg = 0; reg < 4; reg++) {
        int oc = wave * 16 + quad * 4 + reg;
        float bv = bias[oc];
#pragma unroll
        for (int j = 0; j < 4; j++) {
            int px = j * 16 + l16;
            tileT[px * 72 + oc] = f2bf(fmaxf(acc[j][reg] + bv, 0.f));
        }
    }
    __syncthreads();
    int px = t >> 2, part = t & 3;
    int ox = ox0 + px;
    if (ox < 400) {
        int row = (oy + 1) * 402 + ox + 1;
        uint4 v0 = *(const uint4*)(tileT + px * 72 + part * 16);
        uint4 v1 = *(const uint4*)(tileT + px * 72 + part * 16 + 8);
        *(uint4*)(f1t + row * 64 + part * 16) = v0;
        *(uint4*)(f1t + row * 64 + part * 16 + 8) = v1;
    }
}

// conv1 + iou_pass1 fused launch
__global__ __launch_bounds__(256, 4) void conv1_iou1(const unsigned short* __restrict__ imgb,
                                                     const unsigned short* __restrict__ wA,
                                                     const float* __restrict__ bias,
                                                     unsigned short* __restrict__ f1t,
                                                     const float* __restrict__ gt,
                                                     int* __restrict__ aarg,
                                                     unsigned int* __restrict__ gtmax) {
    int t = threadIdx.x;
    if (blockIdx.x < 7) {
        conv1_body(blockIdx.x, blockIdx.y, t, imgb, wA, bias, f1t);
    } else {
        int bid = blockIdx.y;
        if (bid < 352) iou1_body(bid, t, gt, aarg, gtmax);
    }
}

// ---------------- implicit-GEMM conv body, 8-wave K-split (R17 structure) ----
// 8 waves = 4 oc-tiles (ow) x 2 K-groups (kg). B tile DMA'd into LDS (linear
// dest + XOR source swizzle: conv2 e^((c>>2)&7), conv3 e^(row&7)); A read
// direct from global (L2) with 1-step VGPR double-buffered prefetch. kg
// partials combined via one LDS round in the dead B buffer. HEAD: 1x1 heads
// fused in epilogue.
template<int ICC, int RS, int S, bool WRT, bool HEAD>
__device__ __forceinline__ void conv_body(int xs, int y, int t,
                                          const unsigned short* __restrict__ Bt,
                                          const unsigned short* __restrict__ A9,
                                          const float* __restrict__ bias,
                                          float* __restrict__ outF,
                                          unsigned short* __restrict__ outT,
                                          const float* __restrict__ wtc,
                                          const float* __restrict__ wtg,
                                          float* __restrict__ cpart,
                                          float* __restrict__ rpart) {
    constexpr int NC = ICC / 64;            // 1 | 4
    constexpr int HC = S * 24 + 3;          // cols: conv2=99, conv3=27
    constexpr int CHW = ICC / 8;            // 16B chunks per col: 8 | 32
    constexpr int TOT = 3 * HC * CHW;       // 2376 | 2592
    constexpr int BOPS = (TOT + 63) / 64;   // 38 | 41
    constexpr int BB = BOPS * 1024;         // 38912 | 41984
    constexpr int SMB0 = HEAD ? (32768 + 256 * 26 * 4) : BB;   // 59392 | BB
    constexpr int SMB = (SMB0 < BB) ? BB : SMB0;
    __shared__ __align__(16) unsigned char smem[SMB];
    unsigned short* blds = (unsigned short*)smem;
    float* sred = (float*)smem;                 // 32 KB kg-reduction scratch (aliases blds)
    float* hlds = (float*)(smem + 32768);       // [256][26] f32 (HEAD only)

    int wave = t >> 6, lane = t & 63;
    int ow = wave & 3, kg = wave >> 2;
    int quad = lane >> 4, l16 = lane & 15;
    int oc0 = ow * 64;
    int pxe0 = min(l16, 24);
    int pxe1 = min(16 + l16, 24);
    int sw0 = pxe0 & 7, sw1 = pxe1 & 7;

    // ---- B staging: DMA, linear dest chunk q; source chunk XOR-swizzled
    for (int o = wave; o < BOPS; o += 8) {
        int q = min(o * 64 + lane, TOT - 1);
        int row = q / CHW;
        int e = q - row * CHW;
        int ky = row / HC;
        int c = row - ky * HC;
        int sz = (S == 4) ? (e ^ ((c >> 2) & 7)) : (e ^ (row & 7));
        dma16(Bt + ((size_t)(S * y + ky) * RS + S * xs * 25 + c) * ICC + sz * 8,
              (char*)smem + o * 1024);
    }

    f32x4 acc[4][2];
#pragma unroll
    for (int mt = 0; mt < 4; mt++)
#pragma unroll
        for (int j = 0; j < 2; j++) acc[mt][j] = (f32x4){0.f, 0.f, 0.f, 0.f};

    const bf16x8* Av = (const bf16x8*)A9;
    __syncthreads();    // drains B DMA

    // flattened per-wave K loop (conv2: 9 steps, kcl=kg; conv3: 36 steps over
    // cc in [kg*18,kg*18+18) x kcl in {0,1}), fully unrolled, A double-buffered.
    constexpr int NS = (NC == 1) ? 9 : 36;
    bf16x8 afA[4], afB[4];
    {
        int cc0 = (NC == 1) ? 0 : kg * 18;
        int kl0 = (NC == 1) ? kg : 0;
#pragma unroll
        for (int mt = 0; mt < 4; mt++)
            afA[mt] = Av[(size_t)cc0 * 2048 + (ow * 4 + mt) * 128 + kl0 * 64 + lane];
    }
    auto kstep = [&](int s, bf16x8 (&cur)[4], bf16x8 (&nxt)[4]) {
        int cc  = (NC == 1) ? s : kg * 18 + (s >> 1);
        int kcl = (NC == 1) ? kg : (s & 1);
        int pass = cc / NC, ch = cc - pass * NC;
        int ky = pass / 3, kx = pass - (pass / 3) * 3;
        int row0 = ky * HC + S * pxe0 + kx;
        int row1 = ky * HC + S * pxe1 + kx;
        int ck = kcl * 4 + quad;
        int chunk0 = (S == 4) ? (ck ^ sw0) : ((ch * 8 + ck) ^ (row0 & 7));
        int chunk1 = (S == 4) ? (ck ^ sw1) : ((ch * 8 + ck) ^ (row1 & 7));
        bf16x8 bf0 = *(const bf16x8*)(blds + row0 * ICC + chunk0 * 8);
        bf16x8 bf1 = *(const bf16x8*)(blds + row1 * ICC + chunk1 * 8);
        if (s + 1 < NS) {
            int cn = (NC == 1) ? (s + 1) : kg * 18 + ((s + 1) >> 1);
            int kn = (NC == 1) ? kg : ((s + 1) & 1);
#pragma unroll
            for (int mt = 0; mt < 4; mt++)
                nxt[mt] = Av[(size_t)cn * 2048 + (ow * 4 + mt) * 128 + kn * 64 + lane];
        }
#pragma unroll
        for (int mt = 0; mt < 4; mt++) {
            acc[mt][0] = __builtin_amdgcn_mfma_f32_16x16x32_bf16(cur[mt], bf0, acc[mt][0], 0, 0, 0);
            acc[mt][1] = __builtin_amdgcn_mfma_f32_16x16x32_bf16(cur[mt], bf1, acc[mt][1], 0, 0, 0);
        }
    };
#pragma unroll
    for (int s2 = 0; s2 < NS; s2 += 2) {
        kstep(s2, afA, afB);
        if (s2 + 1 < NS) kstep(s2 + 1, afB, afA);
    }

    // combine kg partials: kg1 dumps into (now dead) B buffer, kg0 adds.
    __syncthreads();
    if (kg == 1) {
#pragma unroll
        for (int mt = 0; mt < 4; mt++)
#pragma unroll
            for (int j = 0; j < 2; j++)
                *(f32x4*)(sred + ((((ow * 4 + mt) * 2 + j) * 64 + lane) * 4)) = acc[mt][j];
    }
    __syncthreads();
    if (kg == 0) {
#pragma unroll
        for (int mt = 0; mt < 4; mt++)
#pragma unroll
            for (int j = 0; j < 2; j++) {
                f32x4 o = *(const f32x4*)(sred + ((((ow * 4 + mt) * 2 + j) * 64 + lane) * 4));
                acc[mt][j] = acc[mt][j] + o;
            }
#pragma unroll
        for (int mt = 0; mt < 4; mt++) {
#pragma unroll
            for (int reg = 0; reg < 4; reg++) {
                int oc = oc0 + mt * 16 + quad * 4 + reg;
                float bv = bias[oc];
#pragma unroll
                for (int j = 0; j < 2; j++) {
                    int pl = j * 16 + l16;
                    if (pl < 25) {
                        float v = fmaxf(acc[mt][j][reg] + bv, 0.f);
                        if (HEAD) {
                            hlds[oc * 26 + pl] = v;
                        } else {
                            int p = y * 100 + xs * 25 + pl;
                            outF[oc * 10000 + p] = v;
                            if (WRT) {
                                int r = (y + 1) * 102 + xs * 25 + pl + 1;
                                outT[r * 256 + oc] = f2bf(v);
                            }
                        }
                    }
                }
            }
        }
    }
    if (HEAD) {
        __syncthreads();
        int base = y * 100 + xs * 25;
        // 5400 items: ch(4) x j(54) x p(25); 64-MAC dot each, ic ascending
        for (int it = t; it < 5400; it += 512) {
            int ch = it / 1350;
            int r = it - ch * 1350;
            int j = r / 25;
            int p = r - j * 25;
            int jc = (j < 18) ? j : (j - 18);
            const float* wt = (j < 18) ? (wtc + jc) : (wtg + jc);
            int stride = (j < 18) ? 18 : 36;
            int ic0 = ch * 64;
            float acc2 = 0.f;
#pragma unroll 8
            for (int ic = 0; ic < 64; ic++)
                acc2 += hlds[(ic0 + ic) * 26 + p] * wt[(ic0 + ic) * stride];
            float* dst = (j < 18) ? (cpart + (ch * 18 + jc) * 10000)
                                  : (rpart + (ch * 36 + jc) * 10000);
            dst[base + p] = acc2;
        }
    }
}

// conv2 + iou_pass2 fused launch
__global__ __launch_bounds__(512, 4) void conv2_iou2(const unsigned short* __restrict__ Bt,
                                                     const unsigned short* __restrict__ A9,
                                                     const float* __restrict__ bias,
                                                     float* __restrict__ outF,
                                                     unsigned short* __restrict__ outT,
                                                     const float* __restrict__ gt,
                                                     const unsigned int* __restrict__ gtmax,
                                                     unsigned long long* __restrict__ negmask,
                                                     unsigned long long* __restrict__ posmask,
                                                     float* __restrict__ cand_s,
                                                     int* __restrict__ cand_i,
                                                     unsigned int* __restrict__ cnt) {
    int t = threadIdx.x;
    if (blockIdx.x < 4) {
        conv_body<64, 402, 4, true, false>(blockIdx.x, blockIdx.y, t, Bt, A9, bias,
                                           outF, outT, nullptr, nullptr, nullptr, nullptr);
    } else {
        int bid = (blockIdx.x - 4) * 100 + blockIdx.y;
        if (bid < 176) iou2_body(bid, t, gt, gtmax, negmask, posmask, cand_s, cand_i, cnt);
    }
}

// conv3 + heads fused launch
__global__ __launch_bounds__(512, 4) void conv3_head(const unsigned short* __restrict__ Bt,
                                                     const unsigned short* __restrict__ A9,
                                                     const float* __restrict__ bias,
                                                     const float* __restrict__ wtc,
                                                     const float* __restrict__ wtg,
                                                     float* __restrict__ cpart,
                                                     float* __restrict__ rpart) {
    conv_body<256, 102, 1, false, true>(blockIdx.x, blockIdx.y, threadIdx.x, Bt, A9, bias,
                                        nullptr, nullptr, wtc, wtg, cpart, rpart);
}

// ---------------- single-wave helpers ----------------
__device__ __forceinline__ unsigned long long shflx64(unsigned long long v, int m) {
    int lo = __shfl_xor((int)(unsigned)(v & 0xFFFFFFFFull), m);
    int hi = __shfl_xor((int)(unsigned)(v >> 32), m);
    return ((unsigned long long)(unsigned)hi << 32) | (unsigned)lo;
}

// first-32 set bits (ascending index) of the 90000-bit mask; single wave, no barriers
__device__ int wave_first32(const unsigned long long* __restrict__ mask,
                            bool invert, int* __restrict__ outIdx, int lane) {
    const int NW = 1407;            // ceil(90000/64)
    const int WPT = 22;             // 64*22 = 1408 >= 1407
    unsigned long long mw[WPT];
    int cnt = 0;
#pragma unroll
    for (int u = 0; u < WPT; u++) {
        int w = lane * WPT + u;
        unsigned long long m = 0ull;
        if (w < NW) {
            m = mask[w];
            if (invert) m = ~m;
            if (w == NW - 1) m &= 0xFFFFull;    // anchors 89984..89999 only
        }
        mw[u] = m;
        cnt += __builtin_popcountll(m);
    }
    int inc = cnt;                  // inclusive prefix over lanes via shuffles
#pragma unroll
    for (int off = 1; off < 64; off <<= 1) {
        int v = __shfl_up(inc, off);
        if (lane >= off) inc += v;
    }
    int total = __shfl(inc, 63);
    int pref = inc - cnt;           // exclusive prefix
    if (pref < 32) {
#pragma unroll
        for (int u = 0; u < WPT; u++) {
            unsigned long long m = mw[u];
            int wbase = (lane * WPT + u) * 64;
            while (m && pref < 32) {
                int b = __builtin_ctzll(m);
                outIdx[pref++] = wbase + b;
                m &= m - 1;
            }
        }
    }
    return total;
}

// ---------------- tail: top-k selection + proposals + losses (one wave) ----------------
__global__ __launch_bounds__(64) void tail_kernel(const unsigned long long* __restrict__ negmask,
                                                  const unsigned long long* __restrict__ posmask,
                                                  const float* __restrict__ cand_s,
                                                  const int* __restrict__ cand_i,
                                                  const unsigned int* __restrict__ cnt,
                                                  const float* __restrict__ cpart,
                                                  const float* __restrict__ rpart,
                                                  const float* __restrict__ bcls,
                                                  const float* __restrict__ breg,
                                                  const int* __restrict__ aarg,
                                                  const float* __restrict__ gt,
                                                  const int* __restrict__ gtc,
                                                  float* __restrict__ out) {
    __shared__ unsigned long long keys[CAP + 32];
    __shared__ int sfill[32];
    __shared__ int spidx[32];
    __shared__ int snidx[32];
    int lane = threadIdx.x;

    // ---- build sort keys: (monotonic(score) << 32) | ~index  => max = (score desc, idx asc)
    int ncand = min((int)*cnt, CAP);
    for (int c = lane; c < ncand; c += 64) {
        unsigned u = __float_as_uint(cand_s[c]);
        u ^= (u & 0x80000000u) ? 0xFFFFFFFFu : 0x80000000u;
        keys[c] = ((unsigned long long)u << 32) | (0xFFFFFFFFu - (unsigned)cand_i[c]);
    }
    int ntot = ncand;
    if (ncand < 32) {               // jax top_k tie fill: first label!=1 anchors at value -1
        int tot = wave_first32(posmask, true, sfill, lane);
        int nfill = min(tot, 32);
        unsigned um1 = __float_as_uint(-1.0f) ^ 0xFFFFFFFFu;
        for (int k2 = lane; k2 < nfill; k2 += 64)
            keys[ncand + k2] = ((unsigned long long)um1 << 32) | (0xFFFFFFFFu - (unsigned)sfill[k2]);
        ntot += nfill;
    }

    // ---- 32 rounds of wave argmax; lane owns slots c == lane (mod 64)
    unsigned long long lk = 0ull; int ls = -1;
    for (int c = lane; c < ntot; c += 64) {
        unsigned long long k = keys[c];
        if (k > lk) { lk = k; ls = c; }
    }
    for (int s = 0; s < 32; s++) {
        unsigned long long mk = lk;
#pragma unroll
        for (int off = 1; off < 64; off <<= 1) {
            unsigned long long o = shflx64(mk, off);
            if (o > mk) mk = o;
        }
        if (lk == mk && mk != 0ull) {   // unique winner (keys embed unique indices)
            spidx[s] = (int)(0xFFFFFFFFu - (unsigned)(mk & 0xFFFFFFFFull));
            keys[ls] = 0ull;
            lk = 0ull; ls = -1;
            for (int c = lane; c < ntot; c += 64) {
                unsigned long long k = keys[c];
                if (k > lk) { lk = k; ls = c; }
            }
        }
    }

    // ---- negatives: first 32 label==0 anchors (ascending index)
    int totn = wave_first32(negmask, false, snidx, lane);
    if (lane == 0) {
        int nf = min(totn, 32);
        for (int s = nf; s < 32; s++) snidx[s] = s;   // degenerate fallback
    }

    // ---- finalize (same math as before) ----
    {
#pragma clang fp contract(off)
        const int PROP_OFF = 1 + 2560000;
        int t = lane;
        int n = (t < 32) ? spidx[t] : snidx[t - 32];
        int a = n % 9;
        int q = n / 9;
        int iy = q % 100;
        int ix = q / 100;
        int p = iy * 100 + ix;

        float l0 = bcls[a * 2 + 0], l1 = bcls[a * 2 + 1];
        for (int c = 0; c < 4; c++) {
            l0 += cpart[(c * 18 + a * 2 + 0) * 10000 + p];
            l1 += cpart[(c * 18 + a * 2 + 1) * 10000 + p];
        }
        float m = fmaxf(l0, l1);
        float lse = m + logf(expf(l0 - m) + expf(l1 - m));
        float logp = ((t < 32) ? l1 : l0) - lse;
        float cls_sum = logp;
#pragma unroll
        for (int off = 32; off > 0; off >>= 1) cls_sum += __shfl_down(cls_sum, off);

        float reg_sum = 0.f;
        if (t < 32) {
            float offv[4];
#pragma unroll
            for (int k = 0; k < 4; k++) {
                float v = breg[a * 4 + k];
                for (int c = 0; c < 4; c++) v += rpart[(c * 36 + a * 4 + k) * 10000 + p];
                offv[k] = v;
            }
            float x0, y0, x1, y1, aa;
            anchor_box(n, x0, y0, x1, y1, aa);
            float w = x1 - x0, h = y1 - y0;
            float cx = x0 + 0.5f * w, cy = y0 + 0.5f * h;
            float ncx = cx + offv[0] * w, ncy = cy + offv[1] * h;
            float nw = w * expf(offv[2]), nh = h * expf(offv[3]);
            out[PROP_OFF + t * 4 + 0] = ncx - nw * 0.5f;
            out[PROP_OFF + t * 4 + 1] = ncy - nh * 0.5f;
            out[PROP_OFF + t * 4 + 2] = ncx + nw * 0.5f;
            out[PROP_OFF + t * 4 + 3] = ncy + nh * 0.5f;

            int j = aarg[n];
            float g0 = gt[j * 4 + 0], g1 = gt[j * 4 + 1];
            float g2 = gt[j * 4 + 2], g3 = gt[j * 4 + 3];
            float gw = g2 - g0, gh = g3 - g1;
            float gcx = g0 + 0.5f * gw, gcy = g1 + 0.5f * gh;
            float tg[4];
            tg[0] = (gcx - cx) / w;
            tg[1] = (gcy - cy) / h;
            tg[2] = logf(gw / w);
            tg[3] = logf(gh / h);
#pragma unroll
            for (int k = 0; k < 4; k++) {
                float d = tg[k] - offv[k];
                float ad = fabsf(d);
                reg_sum += (ad < 1.f) ? 0.5f * d * d : ad - 0.5f;
            }
            out[PROP_OFF + 128 + t] = (float)n;
            out[PROP_OFF + 160 + t] = (float)gtc[j];
        }
#pragma unroll
        for (int off = 32; off > 0; off >>= 1) reg_sum += __shfl_down(reg_sum, off);
        if (t == 0) {
            float cls_loss = -(cls_sum / 64.f);
            float reg_loss = reg_sum / 128.f;
            out[0] = cls_loss + 5.f * reg_loss;
        }
    }
}

// ---------------- launch ----------------
extern "C" void kernel_launch(void* const* d_in, const int* in_sizes, int n_in,
                              void* d_out, int out_size, void* d_ws, size_t ws_size,
                              hipStream_t stream) {
    const float* img = (const float*)d_in[0];
    const float* gt  = (const float*)d_in[1];
    const int*   gtc = (const int*)d_in[2];
    const float* w1  = (const float*)d_in[3];
    const float* b1  = (const float*)d_in[4];
    const float* w2  = (const float*)d_in[5];
    const float* b2  = (const float*)d_in[6];
    const float* wr  = (const float*)d_in[7];
    const float* br  = (const float*)d_in[8];
    const float* wc  = (const float*)d_in[9];
    const float* bc  = (const float*)d_in[10];
    const float* wg  = (const float*)d_in[11];
    const float* bg  = (const float*)d_in[12];
    float* out = (float*)d_out;
    float* ws = (float*)d_ws;

    unsigned short* f1t  = (unsigned short*)(ws + OFF_F1T);
    unsigned short* fmt  = (unsigned short*)(ws + OFF_FMT);
    unsigned short* wa1  = (unsigned short*)(ws + OFF_WA1);
    unsigned short* w9_2 = (unsigned short*)(ws + OFF_W9_2);
    unsigned short* w9_3 = (unsigned short*)(ws + OFF_W9_3);
    unsigned short* imgb = (unsigned short*)(ws + OFF_IMGB);
    float* cpart = ws + OFF_CPART;
    float* rpart = ws + OFF_RPART;
    float* wtc   = ws + OFF_WTC;
    float* wtg   = ws + OFF_WTG;
    int*   aarg  = (int*)(ws + OFF_AARG);
    unsigned long long* negm = (unsigned long long*)(ws + OFF_NEGM);
    unsigned long long* posm = (unsigned long long*)(ws + OFF_POSM);
    unsigned int* gtmax = (unsigned int*)(ws + OFF_GTMAX);
    unsigned int* cnt   = gtmax + 64;
    float* cands = ws + OFF_CANDS;
    int*   candi = (int*)(ws + OFF_CANDI);
    float* fm    = out + 1;   // fm lives directly in the output buffer (f32)

    setup_kernel<<<dim3(7192), dim3(256), 0, stream>>>(wc, wtc, wg, wtg, w1, wa1,
                                                       w2, w9_2, wr, w9_3,
                                                       (unsigned int*)f1t, (unsigned int*)fmt, gtmax,
                                                       img, imgb);

    conv1_iou1<<<dim3(8, 400), dim3(256), 0, stream>>>(imgb, wa1, b1, f1t, gt, aarg, gtmax);
    conv2_iou2<<<dim3(6, 100), dim3(512), 0, stream>>>(f1t, w9_2, b2, fm, fmt,
                                                       gt, gtmax, negm, posm, cands, candi, cnt);
    conv3_head<<<dim3(4, 100), dim3(512), 0, stream>>>(fmt, w9_3, br, wtc, wtg, cpart, rpart);
    tail_kernel<<<dim3(1), dim3(64), 0, stream>>>(negm, posm, cands, candi, cnt,
                                                  cpart, rpart, bc, bg, aarg, gt, gtc, out);
}

// Round 12
// 268.219 us; speedup vs baseline: 1.1414x; 1.0084x over previous
//
#include <hip/hip_runtime.h>
#include <math.h>

// RegionProposalNetwork on MI355X (gfx950).
// Round 24: asm-pinned A-prefetch in conv_body.
//  R23's VGPR=52 proved the compiler AGAIN deleted the afA/afB double-buffer
//  (C++ loads re-serialize under pressure; rounds 15-17 same disease). Fix:
//  inline-asm global_load_dwordx4 into 3 rotating register sets (depth-2
//  prefetch), manual counted s_waitcnt vmcnt(8/4/0) + sched_barrier(0)
//  (guide rule #18). Only our asm loads touch vmcnt inside the loop.
//  Everything else identical to R23 (270.5us, absmax 8.0).

#define CAP 4096

typedef __attribute__((ext_vector_type(8))) short bf16x8;
typedef __attribute__((ext_vector_type(4))) float f32x4;

// async 16B/lane global->LDS DMA (dest = wave-uniform base + lane*16)
__device__ __forceinline__ void dma16(const void* g, void* l) {
    __builtin_amdgcn_global_load_lds((const __attribute__((address_space(1))) void*)g,
                                     (__attribute__((address_space(3))) void*)l, 16, 0, 0);
}

// asm-pinned 16B global load: cannot be collapsed/serialized by the scheduler
__device__ __forceinline__ void gload16(bf16x8& d, const unsigned short* p) {
    asm volatile("global_load_dwordx4 %0, %1, off" : "=v"(d) : "v"(p));
}

// ---------------- workspace layout (float offsets) ----------------
#define OFF_F1T     0          // 5,171,328 f = 402*402*64 bf16 (conv1 out, padded transposed)
#define OFF_FMT     5171328    // 1,331,712 f = 102*102*256 bf16 (fm, padded transposed)
#define OFF_CPART   6503040    //   720,000 (4*18*10000)
#define OFF_RPART   7223040    // 1,440,000 (4*36*10000)
#define OFF_WA1     8663040    //     6,144 f = 64*192 bf16 (conv1 weights, K'=192)
#define OFF_W9_2    8672448    //    73,728 f = bf16, [(cc*16+ocT)*2+kcl][lane][8]
#define OFF_W9_3    8746176    //   294,912 f = bf16, same chunking; cc = kk*4+chv
#define OFF_WTC     9041088    //     4,608 [256][18] f32
#define OFF_WTG     9045696    //     9,216 [256][36] f32
#define OFF_AARG    9054912    //    90,000 (int)
#define OFF_NEGM    9144912    //     2,816 f = 1408 uint64 (neg label bitmask)
#define OFF_POSM    9147728    //     2,816 f = 1408 uint64 (pos label bitmask)
#define OFF_GTMAX   9150544    //    64 uint + counter (pad 80)
#define OFF_CANDS   9150688    //    4,096
#define OFF_CANDI   9154784    //    4,096 (int)
#define OFF_IMGB    9158880    // 3,897,792 f = 3*1608*1616 bf16 (padded bf16 image, left pad 11)

__device__ __forceinline__ unsigned short f2bf(float f) {   // RNE f32->bf16
    unsigned int u = __float_as_uint(f);
    u += 0x7fffu + ((u >> 16) & 1u);
    return (unsigned short)(u >> 16);
}

// ---------------- selection-path exact math ----------------
__device__ __forceinline__ void anchor_box(int i, float& x0, float& y0,
                                           float& x1, float& y1, float& area) {
#pragma clang fp contract(off)
    const float sizes[3]  = {128.f, 256.f, 512.f};
    const float ratios[3] = {0.5f, 1.f, 2.f};
    int a = i % 9;
    int q = i / 9;
    int iy = q % 100;
    int ix = q / 100;
    int s = a / 3, r = a % 3;
    float sq = sqrtf(ratios[r]);
    float w = sizes[s] * sq;
    float h = sizes[s] / sq;
    float cx = ((float)ix + 0.5f) * 16.0f;
    float cy = ((float)iy + 0.5f) * 16.0f;
    x0 = cx - w * 0.5f;
    y0 = cy - h * 0.5f;
    x1 = x0 + w;
    y1 = y0 + h;
    area = (x1 - x0) * (y1 - y0);
}

__device__ __forceinline__ float iou_one(float ax0, float ay0, float ax1, float ay1, float aa,
                                         float bx0, float by0, float bx1, float by1, float ab) {
#pragma clang fp contract(off)
    float ltx = fmaxf(ax0, bx0), lty = fmaxf(ay0, by0);
    float rbx = fminf(ax1, bx1), rby = fminf(ay1, by1);
    float iw = fmaxf(rbx - ltx, 0.0f);
    float ih = fmaxf(rby - lty, 0.0f);
    float inter = iw * ih;
    return inter / ((aa + ab) - inter);
}

// ---------------- merged setup: counters, borders, weights, bf16 image ----------------
__global__ __launch_bounds__(256) void setup_kernel(const float* __restrict__ wc, float* __restrict__ wtc,
                                                    const float* __restrict__ wg, float* __restrict__ wtg,
                                                    const float* __restrict__ w1, unsigned short* __restrict__ wa1,
                                                    const float* __restrict__ w2, unsigned short* __restrict__ w9_2,
                                                    const float* __restrict__ wr, unsigned short* __restrict__ w9_3,
                                                    unsigned int* __restrict__ f1t_u, unsigned int* __restrict__ fmt_u,
                                                    unsigned int* __restrict__ gtmax,
                                                    const float* __restrict__ img, unsigned short* __restrict__ imgb) {
    int i = blockIdx.x * 256 + threadIdx.x;
    if (i < 65) { gtmax[i] = 0u; return; }
    i -= 65;
    if (i < 103040) {   // zero pad borders of f1t / fmt
        if (i < 51328) {
            int p = i >> 5, part = i & 31;
            int x, y;
            if (p < 804) { y = (p < 402) ? 0 : 401; x = p % 402; }
            else { int j = p - 804; x = (j < 400) ? 0 : 401; y = 1 + (j % 400); }
            f1t_u[(y * 402 + x) * 32 + part] = 0u;
        } else {
            int i2 = i - 51328;
            int p = i2 >> 7, part = i2 & 127;
            int x, y;
            if (p < 204) { y = (p < 102) ? 0 : 101; x = p % 102; }
            else { int j = p - 204; x = (j < 100) ? 0 : 101; y = 1 + (j % 100); }
            fmt_u[(y * 102 + x) * 128 + part] = 0u;
        }
        return;
    }
    i -= 103040;
    if (i < 4608) { int c = i / 256, k = i - c * 256; wtc[k * 18 + c] = wc[i]; return; }
    i -= 4608;
    if (i < 9216) { int c = i / 256, k = i - c * 256; wtg[k * 36 + c] = wg[i]; return; }
    i -= 9216;
    if (i < 12288) {    // conv1 weights -> [oc][k'], k' = (ky*3+ic)*8 + kx, K'=192
        int oc = i / 192, k = i - oc * 192;
        int q = k >> 3, kx = k & 7;
        int ky = q / 3, ic = q - (q / 3) * 3;
        wa1[i] = (q < 21 && kx < 7) ? f2bf(w1[oc * 147 + ic * 49 + ky * 7 + kx])
                                    : (unsigned short)0;
        return;
    }
    i -= 12288;
    if (i < 147456) {   // conv2 weights, chunked: i = ((cc*16+ocT)*2+kcl)*512 + lane*8 + e
        int cc = i >> 14;
        int rem = i & 16383;
        int ocT = rem >> 10;
        int rem2 = rem & 1023;
        int kcl = rem2 >> 9;
        int lane = (rem2 & 511) >> 3;
        int e = rem2 & 7;
        int oc = ocT * 16 + (lane & 15);
        int ic = kcl * 32 + (lane >> 4) * 8 + e;
        w9_2[i] = f2bf(w2[(oc * 64 + ic) * 9 + cc]);
        return;
    }
    i -= 147456;
    if (i < 589824) {   // conv3 weights, chunked; cc = kk*4+chv
        int cc = i >> 14;
        int rem = i & 16383;
        int ocT = rem >> 10;
        int rem2 = rem & 1023;
        int kcl = rem2 >> 9;
        int lane = (rem2 & 511) >> 3;
        int e = rem2 & 7;
        int kk = cc >> 2, chv = cc & 3;
        int oc = ocT * 16 + (lane & 15);
        int icl = kcl * 32 + (lane >> 4) * 8 + e;
        w9_3[i] = f2bf(wr[(oc * 256 + chv * 64 + icl) * 9 + kk]);
        return;
    }
    i -= 589824;
    if (i < 974448) {   // bf16 image, vectorized: 3 ch x 1608 rows x 202 chunks of 8
        int ic = i / 324816;
        int rem = i - ic * 324816;
        int row = rem / 202;            // padded row 0..1607
        int k = rem - row * 202;        // chunk 0..201
        int y = row - 3;                // img y
        bool yok = (y >= 0) && (y < 1600);
        int yc = min(max(y, 0), 1599);
        const float* srow = img + ((size_t)(ic * 1600 + yc)) * 1600;
        unsigned int d[4];
#pragma unroll
        for (int e2 = 0; e2 < 4; e2++) {
            int x0 = k * 8 + 2 * e2 - 11;
            int x1 = x0 + 1;
            bool ok0 = yok && (x0 >= 0) && (x0 < 1600);
            bool ok1 = yok && (x1 >= 0) && (x1 < 1600);
            float f0 = srow[min(max(x0, 0), 1599)];
            float f1 = srow[min(max(x1, 0), 1599)];
            unsigned int lo = ok0 ? (unsigned int)f2bf(f0) : 0u;
            unsigned int hi = ok1 ? (unsigned int)f2bf(f1) : 0u;
            d[e2] = lo | (hi << 16);
        }
        *(uint4*)(imgb + ((size_t)(ic * 1608 + row)) * 1616 + k * 8) =
            make_uint4(d[0], d[1], d[2], d[3]);
    }
}

// ---------------- iou pass bodies (fused into conv launches) ----------------
__device__ __forceinline__ void iou1_body(int bid, int t, const float* __restrict__ gt,
                                          int* __restrict__ aarg, unsigned int* __restrict__ gtmax) {
    __shared__ float sg1[64][4];
    __shared__ float sarea1[64];
    __shared__ unsigned int smax1[64];
    if (t < 64) {
#pragma clang fp contract(off)
        float b0 = gt[t * 4 + 0], b1 = gt[t * 4 + 1];
        float b2 = gt[t * 4 + 2], b3 = gt[t * 4 + 3];
        sg1[t][0] = b0; sg1[t][1] = b1; sg1[t][2] = b2; sg1[t][3] = b3;
        sarea1[t] = (b2 - b0) * (b3 - b1);
        smax1[t] = 0u;
    }
    __syncthreads();
    int i = bid * 256 + t;
    int iq = min(i, 89999);
    float x0, y0, x1, y1, aa;
    anchor_box(iq, x0, y0, x1, y1, aa);
    float best = -1.f;
    int bestj = 0;
    for (int j = 0; j < 64; j++) {
        float v = iou_one(x0, y0, x1, y1, aa, sg1[j][0], sg1[j][1], sg1[j][2], sg1[j][3], sarea1[j]);
        if (v > best) { best = v; bestj = j; }
        // filtered exact max: snapshot read + monotonic atomicMax (no miss possible)
        if (v > __uint_as_float(smax1[j])) atomicMax(&smax1[j], __float_as_uint(v));
    }
    if (i < 90000) aarg[i] = bestj;
    __syncthreads();
    if (t < 64) atomicMax(&gtmax[t], smax1[t]);
}

__device__ __forceinline__ void iou2_body(int bid, int t, const float* __restrict__ gt,
                                          const unsigned int* __restrict__ gtmax,
                                          unsigned long long* __restrict__ negmask,
                                          unsigned long long* __restrict__ posmask,
                                          float* __restrict__ cand_s, int* __restrict__ cand_i,
                                          unsigned int* __restrict__ cnt) {
    __shared__ float sg2[64][4];
    __shared__ float sarea2[64];
    __shared__ float sgm2[64];
    if (t < 64) {
#pragma clang fp contract(off)
        float b0 = gt[t * 4 + 0], b1 = gt[t * 4 + 1];
        float b2 = gt[t * 4 + 2], b3 = gt[t * 4 + 3];
        sg2[t][0] = b0; sg2[t][1] = b1; sg2[t][2] = b2; sg2[t][3] = b3;
        sarea2[t] = (b2 - b0) * (b3 - b1);
        sgm2[t] = __uint_as_float(gtmax[t]);
    }
    __syncthreads();
    int i = bid * 512 + t;
    if (i >= 90000) return;
    float x0, y0, x1, y1, aa;
    anchor_box(i, x0, y0, x1, y1, aa);
    float best = -1.f;
    bool isbest = false;
    for (int j = 0; j < 64; j++) {
        float v = iou_one(x0, y0, x1, y1, aa, sg2[j][0], sg2[j][1], sg2[j][2], sg2[j][3], sarea2[j]);
        if (v > best) best = v;
        if (v == sgm2[j]) isbest = true;   // exact equality, identical f32 code path as pass 1
    }
    float label = -1.f;
    if (best < 0.2f) label = 0.f;
    if (isbest) label = 1.f;
    if (best > 0.7f) label = 1.f;
    unsigned long long negb = __ballot(label == 0.f);
    unsigned long long posb = __ballot(label == 1.f);
    if ((t & 63) == 0) { negmask[i >> 6] = negb; posmask[i >> 6] = posb; }
    if (label == 1.f) {
        unsigned int p = atomicAdd(cnt, 1u);
        if (p < CAP) { cand_s[p] = best; cand_i[p] = i; }
    }
}

// ---------------- conv1 body via MFMA: 3->64, 7x7, s4, p3 ----------------
// bf16 image pre-padded (pad 11 left / stride 1616 / 3 top rows zero).
// 13 DMA ops land win[24][264] directly; rows 21-23 + slack from zero rows.
__device__ __forceinline__ void conv1_body(int bx, int oy, int t,
                                           const unsigned short* __restrict__ imgb,
                                           const unsigned short* __restrict__ wA,
                                           const float* __restrict__ bias,
                                           unsigned short* __restrict__ f1t) {
    __shared__ __align__(16) unsigned char smem[13312];   // 13 ops x 1024B
    unsigned short* win = (unsigned short*)smem;          // [24][264] = 12,672 B
    unsigned short* tileT = (unsigned short*)smem;        // [64][72] alias after MFMA
    int wave = t >> 6, lane = t & 63;
    int quad = lane >> 4, l16 = lane & 15;
    int ox0 = bx * 64;
    int col0 = ox0 * 4 + 8;             // img x = ox0*4-3 at win col 0; mult of 8 -> 16B aligned
    int gy0 = 4 * oy - 3;

    // 13 DMA ops, 3-4 per wave; chunk q -> win row q/33, col chunk q%33
    for (int o = wave; o < 13; o += 4) {
        int q = o * 64 + lane;
        int r = q / 33;
        int c = q - r * 33;
        int rc = min(r, 20);
        int ky = rc / 3, ic = rc - (rc / 3) * 3;
        int yp = gy0 + ky + 3;          // in [0,1605]
        size_t offm = ((size_t)(ic * 1608 + yp)) * 1616 + col0 + c * 8;
        size_t offz = (size_t)(q - 693) * 8;   // rows 0-2 of ch0 are all zero
        dma16(imgb + ((r < 21) ? offm : offz), (char*)smem + o * 1024);
    }
    // A fragments (L2-resident weights)
    bf16x8 afr[6];
    {
        const bf16x8* ap = (const bf16x8*)(wA + (wave * 16 + l16) * 192 + quad * 8);
#pragma unroll
        for (int c = 0; c < 6; c++) afr[c] = ap[c * 4];
    }
    __syncthreads();    // drains DMA for all waves

    f32x4 acc[4];
#pragma unroll
    for (int j = 0; j < 4; j++) acc[j] = (f32x4){0.f, 0.f, 0.f, 0.f};
#pragma unroll
    for (int ch = 0; ch < 6; ch++) {
        const unsigned short* wrow = win + (ch * 4 + quad) * 264;
#pragma unroll
        for (int j = 0; j < 4; j++) {
            int px = j * 16 + l16;
            const unsigned long long* bp = (const unsigned long long*)(wrow + 4 * px); // 8B-aligned
            union { unsigned long long u[2]; bf16x8 v; } uu;
            uu.u[0] = bp[0];
            uu.u[1] = bp[1];
            acc[j] = __builtin_amdgcn_mfma_f32_16x16x32_bf16(afr[ch], uu.v, acc[j], 0, 0, 0);
        }
    }
    __syncthreads();    // win dead; tileT aliases it
#pragma unroll
    for (int reg = 0; reg < 4; reg++) {
        int oc = wave * 16 + quad * 4 + reg;
        float bv = bias[oc];
#pragma unroll
        for (int j = 0; j < 4; j++) {
            int px = j * 16 + l16;
            tileT[px * 72 + oc] = f2bf(fmaxf(acc[j][reg] + bv, 0.f));
        }
    }
    __syncthreads();
    int px = t >> 2, part = t & 3;
    int ox = ox0 + px;
    if (ox < 400) {
        int row = (oy + 1) * 402 + ox + 1;
        uint4 v0 = *(const uint4*)(tileT + px * 72 + part * 16);
        uint4 v1 = *(const uint4*)(tileT + px * 72 + part * 16 + 8);
        *(uint4*)(f1t + row * 64 + part * 16) = v0;
        *(uint4*)(f1t + row * 64 + part * 16 + 8) = v1;
    }
}

// conv1 + iou_pass1 fused launch
__global__ __launch_bounds__(256, 4) void conv1_iou1(const unsigned short* __restrict__ imgb,
                                                     const unsigned short* __restrict__ wA,
                                                     const float* __restrict__ bias,
                                                     unsigned short* __restrict__ f1t,
                                                     const float* __restrict__ gt,
                                                     int* __restrict__ aarg,
                                                     unsigned int* __restrict__ gtmax) {
    int t = threadIdx.x;
    if (blockIdx.x < 7) {
        conv1_body(blockIdx.x, blockIdx.y, t, imgb, wA, bias, f1t);
    } else {
        int bid = blockIdx.y;
        if (bid < 352) iou1_body(bid, t, gt, aarg, gtmax);
    }
}

// ---------------- implicit-GEMM conv body, 8-wave K-split ----------
// 8 waves = 4 oc-tiles (ow) x 2 K-groups (kg). B tile DMA'd into LDS (linear
// dest + XOR source swizzle). A loaded via asm-pinned global_load_dwordx4
// into 3 rotating register sets (depth-2 prefetch) with counted manual
// vmcnt(8/4/0) + sched_barrier(0) -- the scheduler cannot re-serialize asm.
// kg partials combined via one LDS round in the dead B buffer. HEAD: heads
// fused in epilogue.
template<int ICC, int RS, int S, bool WRT, bool HEAD>
__device__ __forceinline__ void conv_body(int xs, int y, int t,
                                          const unsigned short* __restrict__ Bt,
                                          const unsigned short* __restrict__ A9,
                                          const float* __restrict__ bias,
                                          float* __restrict__ outF,
                                          unsigned short* __restrict__ outT,
                                          const float* __restrict__ wtc,
                                          const float* __restrict__ wtg,
                                          float* __restrict__ cpart,
                                          float* __restrict__ rpart) {
    constexpr int NC = ICC / 64;            // 1 | 4
    constexpr int HC = S * 24 + 3;          // cols: conv2=99, conv3=27
    constexpr int CHW = ICC / 8;            // 16B chunks per col: 8 | 32
    constexpr int TOT = 3 * HC * CHW;       // 2376 | 2592
    constexpr int BOPS = (TOT + 63) / 64;   // 38 | 41
    constexpr int BB = BOPS * 1024;         // 38912 | 41984
    constexpr int SMB0 = HEAD ? (32768 + 256 * 26 * 4) : BB;   // 59392 | BB
    constexpr int SMB = (SMB0 < BB) ? BB : SMB0;
    __shared__ __align__(16) unsigned char smem[SMB];
    unsigned short* blds = (unsigned short*)smem;
    float* sred = (float*)smem;                 // 32 KB kg-reduction scratch (aliases blds)
    float* hlds = (float*)(smem + 32768);       // [256][26] f32 (HEAD only)

    int wave = t >> 6, lane = t & 63;
    int ow = wave & 3, kg = wave >> 2;
    int quad = lane >> 4, l16 = lane & 15;
    int oc0 = ow * 64;
    int pxe0 = min(l16, 24);
    int pxe1 = min(16 + l16, 24);
    int sw0 = pxe0 & 7, sw1 = pxe1 & 7;

    // ---- B staging: DMA, linear dest chunk q; source chunk XOR-swizzled
    for (int o = wave; o < BOPS; o += 8) {
        int q = min(o * 64 + lane, TOT - 1);
        int row = q / CHW;
        int e = q - row * CHW;
        int ky = row / HC;
        int c = row - ky * HC;
        int sz = (S == 4) ? (e ^ ((c >> 2) & 7)) : (e ^ (row & 7));
        dma16(Bt + ((size_t)(S * y + ky) * RS + S * xs * 25 + c) * ICC + sz * 8,
              (char*)smem + o * 1024);
    }

    f32x4 acc[4][2];
#pragma unroll
    for (int mt = 0; mt < 4; mt++)
#pragma unroll
        for (int j = 0; j < 2; j++) acc[mt][j] = (f32x4){0.f, 0.f, 0.f, 0.f};

    const bf16x8* Av = (const bf16x8*)A9;
    constexpr int NS = (NC == 1) ? 9 : 36;
    // per (step, mt) A pointer (bf16x8-granular layout, cast to short*)
    auto aptr = [&](int s, int mt) -> const unsigned short* {
        int cc  = (NC == 1) ? s : kg * 18 + (s >> 1);
        int kcl = (NC == 1) ? kg : (s & 1);
        return (const unsigned short*)(Av + (size_t)cc * 2048 + (ow * 4 + mt) * 128 + kcl * 64 + lane);
    };

    // 3 rotating A register sets; asm defs pinned, indices static post-unroll
    bf16x8 aS[3][4];
#pragma unroll
    for (int mt = 0; mt < 4; mt++) gload16(aS[0][mt], aptr(0, mt));
    if (NS > 1) {
#pragma unroll
        for (int mt = 0; mt < 4; mt++) gload16(aS[1][mt], aptr(1, mt));
    }

    __syncthreads();    // drains B DMA + A batches 0,1 (vmcnt(0) + barrier)

#pragma unroll
    for (int s = 0; s < NS; s++) {
        // issue batch s+2 into slot (s+2)%3
        if (s + 2 < NS) {
#pragma unroll
            for (int mt = 0; mt < 4; mt++) gload16(aS[(s + 2) % 3][mt], aptr(s + 2, mt));
        }
        // B fragments for this step (ds_read; DS latency overlaps vmcnt stall)
        int cc  = (NC == 1) ? s : kg * 18 + (s >> 1);
        int kcl = (NC == 1) ? kg : (s & 1);
        int pass = cc / NC, ch = cc - pass * NC;
        int ky = pass / 3, kx = pass - (pass / 3) * 3;
        int row0 = ky * HC + S * pxe0 + kx;
        int row1 = ky * HC + S * pxe1 + kx;
        int ck = kcl * 4 + quad;
        int chunk0 = (S == 4) ? (ck ^ sw0) : ((ch * 8 + ck) ^ (row0 & 7));
        int chunk1 = (S == 4) ? (ck ^ sw1) : ((ch * 8 + ck) ^ (row1 & 7));
        bf16x8 bf0 = *(const bf16x8*)(blds + row0 * ICC + chunk0 * 8);
        bf16x8 bf1 = *(const bf16x8*)(blds + row1 * ICC + chunk1 * 8);
        // wait: only our asm loads count toward vmcnt here. Outstanding at this
        // point = batches s,s+1,s+2 (12) in steady state -> vmcnt(8) lands s.
        if (s + 2 < NS)      asm volatile("s_waitcnt vmcnt(8)" ::: "memory");
        else if (s + 1 < NS) asm volatile("s_waitcnt vmcnt(4)" ::: "memory");
        else                 asm volatile("s_waitcnt vmcnt(0)" ::: "memory");
        __builtin_amdgcn_sched_barrier(0);   // rule #18: MFMA must not hoist above
#pragma unroll
        for (int mt = 0; mt < 4; mt++) {
            acc[mt][0] = __builtin_amdgcn_mfma_f32_16x16x32_bf16(aS[s % 3][mt], bf0, acc[mt][0], 0, 0, 0);
            acc[mt][1] = __builtin_amdgcn_mfma_f32_16x16x32_bf16(aS[s % 3][mt], bf1, acc[mt][1], 0, 0, 0);
        }
    }

    // combine kg partials: kg1 dumps into (now dead) B buffer, kg0 adds.
    __syncthreads();
    if (kg == 1) {
#pragma unroll
        for (int mt = 0; mt < 4; mt++)
#pragma unroll
            for (int j = 0; j < 2; j++)
                *(f32x4*)(sred + ((((ow * 4 + mt) * 2 + j) * 64 + lane) * 4)) = acc[mt][j];
    }
    __syncthreads();
    if (kg == 0) {
#pragma unroll
        for (int mt = 0; mt < 4; mt++)
#pragma unroll
            for (int j = 0; j < 2; j++) {
                f32x4 o = *(const f32x4*)(sred + ((((ow * 4 + mt) * 2 + j) * 64 + lane) * 4));
                acc[mt][j] = acc[mt][j] + o;
            }
#pragma unroll
        for (int mt = 0; mt < 4; mt++) {
#pragma unroll
            for (int reg = 0; reg < 4; reg++) {
                int oc = oc0 + mt * 16 + quad * 4 + reg;
                float bv = bias[oc];
#pragma unroll
                for (int j = 0; j < 2; j++) {
                    int pl = j * 16 + l16;
                    if (pl < 25) {
                        float v = fmaxf(acc[mt][j][reg] + bv, 0.f);
                        if (HEAD) {
                            hlds[oc * 26 + pl] = v;
                        } else {
                            int p = y * 100 + xs * 25 + pl;
                            outF[oc * 10000 + p] = v;
                            if (WRT) {
                                int r = (y + 1) * 102 + xs * 25 + pl + 1;
                                outT[r * 256 + oc] = f2bf(v);
                            }
                        }
                    }
                }
            }
        }
    }
    if (HEAD) {
        __syncthreads();
        int base = y * 100 + xs * 25;
        // 5400 items: ch(4) x j(54) x p(25); 64-MAC dot each, ic ascending
        for (int it = t; it < 5400; it += 512) {
            int ch = it / 1350;
            int r = it - ch * 1350;
            int j = r / 25;
            int p = r - j * 25;
            int jc = (j < 18) ? j : (j - 18);
            const float* wt = (j < 18) ? (wtc + jc) : (wtg + jc);
            int stride = (j < 18) ? 18 : 36;
            int ic0 = ch * 64;
            float acc2 = 0.f;
#pragma unroll 8
            for (int ic = 0; ic < 64; ic++)
                acc2 += hlds[(ic0 + ic) * 26 + p] * wt[(ic0 + ic) * stride];
            float* dst = (j < 18) ? (cpart + (ch * 18 + jc) * 10000)
                                  : (rpart + (ch * 36 + jc) * 10000);
            dst[base + p] = acc2;
        }
    }
}

// conv2 + iou_pass2 fused launch
__global__ __launch_bounds__(512, 4) void conv2_iou2(const unsigned short* __restrict__ Bt,
                                                     const unsigned short* __restrict__ A9,
                                                     const float* __restrict__ bias,
                                                     float* __restrict__ outF,
                                                     unsigned short* __restrict__ outT,
                                                     const float* __restrict__ gt,
                                                     const unsigned int* __restrict__ gtmax,
                                                     unsigned long long* __restrict__ negmask,
                                                     unsigned long long* __restrict__ posmask,
                                                     float* __restrict__ cand_s,
                                                     int* __restrict__ cand_i,
                                                     unsigned int* __restrict__ cnt) {
    int t = threadIdx.x;
    if (blockIdx.x < 4) {
        conv_body<64, 402, 4, true, false>(blockIdx.x, blockIdx.y, t, Bt, A9, bias,
                                           outF, outT, nullptr, nullptr, nullptr, nullptr);
    } else {
        int bid = (blockIdx.x - 4) * 100 + blockIdx.y;
        if (bid < 176) iou2_body(bid, t, gt, gtmax, negmask, posmask, cand_s, cand_i, cnt);
    }
}

// conv3 + heads fused launch
__global__ __launch_bounds__(512, 4) void conv3_head(const unsigned short* __restrict__ Bt,
                                                     const unsigned short* __restrict__ A9,
                                                     const float* __restrict__ bias,
                                                     const float* __restrict__ wtc,
                                                     const float* __restrict__ wtg,
                                                     float* __restrict__ cpart,
                                                     float* __restrict__ rpart) {
    conv_body<256, 102, 1, false, true>(blockIdx.x, blockIdx.y, threadIdx.x, Bt, A9, bias,
                                        nullptr, nullptr, wtc, wtg, cpart, rpart);
}

// ---------------- single-wave helpers ----------------
__device__ __forceinline__ unsigned long long shflx64(unsigned long long v, int m) {
    int lo = __shfl_xor((int)(unsigned)(v & 0xFFFFFFFFull), m);
    int hi = __shfl_xor((int)(unsigned)(v >> 32), m);
    return ((unsigned long long)(unsigned)hi << 32) | (unsigned)lo;
}

// first-32 set bits (ascending index) of the 90000-bit mask; single wave, no barriers
__device__ int wave_first32(const unsigned long long* __restrict__ mask,
                            bool invert, int* __restrict__ outIdx, int lane) {
    const int NW = 1407;            // ceil(90000/64)
    const int WPT = 22;             // 64*22 = 1408 >= 1407
    unsigned long long mw[WPT];
    int cnt = 0;
#pragma unroll
    for (int u = 0; u < WPT; u++) {
        int w = lane * WPT + u;
        unsigned long long m = 0ull;
        if (w < NW) {
            m = mask[w];
            if (invert) m = ~m;
            if (w == NW - 1) m &= 0xFFFFull;    // anchors 89984..89999 only
        }
        mw[u] = m;
        cnt += __builtin_popcountll(m);
    }
    int inc = cnt;                  // inclusive prefix over lanes via shuffles
#pragma unroll
    for (int off = 1; off < 64; off <<= 1) {
        int v = __shfl_up(inc, off);
        if (lane >= off) inc += v;
    }
    int total = __shfl(inc, 63);
    int pref = inc - cnt;           // exclusive prefix
    if (pref < 32) {
#pragma unroll
        for (int u = 0; u < WPT; u++) {
            unsigned long long m = mw[u];
            int wbase = (lane * WPT + u) * 64;
            while (m && pref < 32) {
                int b = __builtin_ctzll(m);
                outIdx[pref++] = wbase + b;
                m &= m - 1;
            }
        }
    }
    return total;
}

// ---------------- tail: top-k selection + proposals + losses (one wave) ----------------
__global__ __launch_bounds__(64) void tail_kernel(const unsigned long long* __restrict__ negmask,
                                                  const unsigned long long* __restrict__ posmask,
                                                  const float* __restrict__ cand_s,
                                                  const int* __restrict__ cand_i,
                                                  const unsigned int* __restrict__ cnt,
                                                  const float* __restrict__ cpart,
                                                  const float* __restrict__ rpart,
                                                  const float* __restrict__ bcls,
                                                  const float* __restrict__ breg,
                                                  const int* __restrict__ aarg,
                                                  const float* __restrict__ gt,
                                                  const int* __restrict__ gtc,
                                                  float* __restrict__ out) {
    __shared__ unsigned long long keys[CAP + 32];
    __shared__ int sfill[32];
    __shared__ int spidx[32];
    __shared__ int snidx[32];
    int lane = threadIdx.x;

    // ---- build sort keys: (monotonic(score) << 32) | ~index  => max = (score desc, idx asc)
    int ncand = min((int)*cnt, CAP);
    for (int c = lane; c < ncand; c += 64) {
        unsigned u = __float_as_uint(cand_s[c]);
        u ^= (u & 0x80000000u) ? 0xFFFFFFFFu : 0x80000000u;
        keys[c] = ((unsigned long long)u << 32) | (0xFFFFFFFFu - (unsigned)cand_i[c]);
    }
    int ntot = ncand;
    if (ncand < 32) {               // jax top_k tie fill: first label!=1 anchors at value -1
        int tot = wave_first32(posmask, true, sfill, lane);
        int nfill = min(tot, 32);
        unsigned um1 = __float_as_uint(-1.0f) ^ 0xFFFFFFFFu;
        for (int k2 = lane; k2 < nfill; k2 += 64)
            keys[ncand + k2] = ((unsigned long long)um1 << 32) | (0xFFFFFFFFu - (unsigned)sfill[k2]);
        ntot += nfill;
    }

    // ---- 32 rounds of wave argmax; lane owns slots c == lane (mod 64)
    unsigned long long lk = 0ull; int ls = -1;
    for (int c = lane; c < ntot; c += 64) {
        unsigned long long k = keys[c];
        if (k > lk) { lk = k; ls = c; }
    }
    for (int s = 0; s < 32; s++) {
        unsigned long long mk = lk;
#pragma unroll
        for (int off = 1; off < 64; off <<= 1) {
            unsigned long long o = shflx64(mk, off);
            if (o > mk) mk = o;
        }
        if (lk == mk && mk != 0ull) {   // unique winner (keys embed unique indices)
            spidx[s] = (int)(0xFFFFFFFFu - (unsigned)(mk & 0xFFFFFFFFull));
            keys[ls] = 0ull;
            lk = 0ull; ls = -1;
            for (int c = lane; c < ntot; c += 64) {
                unsigned long long k = keys[c];
                if (k > lk) { lk = k; ls = c; }
            }
        }
    }

    // ---- negatives: first 32 label==0 anchors (ascending index)
    int totn = wave_first32(negmask, false, snidx, lane);
    if (lane == 0) {
        int nf = min(totn, 32);
        for (int s = nf; s < 32; s++) snidx[s] = s;   // degenerate fallback
    }

    // ---- finalize (same math as before) ----
    {
#pragma clang fp contract(off)
        const int PROP_OFF = 1 + 2560000;
        int t = lane;
        int n = (t < 32) ? spidx[t] : snidx[t - 32];
        int a = n % 9;
        int q = n / 9;
        int iy = q % 100;
        int ix = q / 100;
        int p = iy * 100 + ix;

        float l0 = bcls[a * 2 + 0], l1 = bcls[a * 2 + 1];
        for (int c = 0; c < 4; c++) {
            l0 += cpart[(c * 18 + a * 2 + 0) * 10000 + p];
            l1 += cpart[(c * 18 + a * 2 + 1) * 10000 + p];
        }
        float m = fmaxf(l0, l1);
        float lse = m + logf(expf(l0 - m) + expf(l1 - m));
        float logp = ((t < 32) ? l1 : l0) - lse;
        float cls_sum = logp;
#pragma unroll
        for (int off = 32; off > 0; off >>= 1) cls_sum += __shfl_down(cls_sum, off);

        float reg_sum = 0.f;
        if (t < 32) {
            float offv[4];
#pragma unroll
            for (int k = 0; k < 4; k++) {
                float v = breg[a * 4 + k];
                for (int c = 0; c < 4; c++) v += rpart[(c * 36 + a * 4 + k) * 10000 + p];
                offv[k] = v;
            }
            float x0, y0, x1, y1, aa;
            anchor_box(n, x0, y0, x1, y1, aa);
            float w = x1 - x0, h = y1 - y0;
            float cx = x0 + 0.5f * w, cy = y0 + 0.5f * h;
            float ncx = cx + offv[0] * w, ncy = cy + offv[1] * h;
            float nw = w * expf(offv[2]), nh = h * expf(offv[3]);
            out[PROP_OFF + t * 4 + 0] = ncx - nw * 0.5f;
            out[PROP_OFF + t * 4 + 1] = ncy - nh * 0.5f;
            out[PROP_OFF + t * 4 + 2] = ncx + nw * 0.5f;
            out[PROP_OFF + t * 4 + 3] = ncy + nh * 0.5f;

            int j = aarg[n];
            float g0 = gt[j * 4 + 0], g1 = gt[j * 4 + 1];
            float g2 = gt[j * 4 + 2], g3 = gt[j * 4 + 3];
            float gw = g2 - g0, gh = g3 - g1;
            float gcx = g0 + 0.5f * gw, gcy = g1 + 0.5f * gh;
            float tg[4];
            tg[0] = (gcx - cx) / w;
            tg[1] = (gcy - cy) / h;
            tg[2] = logf(gw / w);
            tg[3] = logf(gh / h);
#pragma unroll
            for (int k = 0; k < 4; k++) {
                float d = tg[k] - offv[k];
                float ad = fabsf(d);
                reg_sum += (ad < 1.f) ? 0.5f * d * d : ad - 0.5f;
            }
            out[PROP_OFF + 128 + t] = (float)n;
            out[PROP_OFF + 160 + t] = (float)gtc[j];
        }
#pragma unroll
        for (int off = 32; off > 0; off >>= 1) reg_sum += __shfl_down(reg_sum, off);
        if (t == 0) {
            float cls_loss = -(cls_sum / 64.f);
            float reg_loss = reg_sum / 128.f;
            out[0] = cls_loss + 5.f * reg_loss;
        }
    }
}

// ---------------- launch ----------------
extern "C" void kernel_launch(void* const* d_in, const int* in_sizes, int n_in,
                              void* d_out, int out_size, void* d_ws, size_t ws_size,
                              hipStream_t stream) {
    const float* img = (const float*)d_in[0];
    const float* gt  = (const float*)d_in[1];
    const int*   gtc = (const int*)d_in[2];
    const float* w1  = (const float*)d_in[3];
    const float* b1  = (const float*)d_in[4];
    const float* w2  = (const float*)d_in[5];
    const float* b2  = (const float*)d_in[6];
    const float* wr  = (const float*)d_in[7];
    const float* br  = (const float*)d_in[8];
    const float* wc  = (const float*)d_in[9];
    const float* bc  = (const float*)d_in[10];
    const float* wg  = (const float*)d_in[11];
    const float* bg  = (const float*)d_in[12];
    float* out = (float*)d_out;
    float* ws = (float*)d_ws;

    unsigned short* f1t  = (unsigned short*)(ws + OFF_F1T);
    unsigned short* fmt  = (unsigned short*)(ws + OFF_FMT);
    unsigned short* wa1  = (unsigned short*)(ws + OFF_WA1);
    unsigned short* w9_2 = (unsigned short*)(ws + OFF_W9_2);
    unsigned short* w9_3 = (unsigned short*)(ws + OFF_W9_3);
    unsigned short* imgb = (unsigned short*)(ws + OFF_IMGB);
    float* cpart = ws + OFF_CPART;
    float* rpart = ws + OFF_RPART;
    float* wtc   = ws + OFF_WTC;
    float* wtg   = ws + OFF_WTG;
    int*   aarg  = (int*)(ws + OFF_AARG);
    unsigned long long* negm = (unsigned long long*)(ws + OFF_NEGM);
    unsigned long long* posm = (unsigned long long*)(ws + OFF_POSM);
    unsigned int* gtmax = (unsigned int*)(ws + OFF_GTMAX);
    unsigned int* cnt   = gtmax + 64;
    float* cands = ws + OFF_CANDS;
    int*   candi = (int*)(ws + OFF_CANDI);
    float* fm    = out + 1;   // fm lives directly in the output buffer (f32)

    setup_kernel<<<dim3(7192), dim3(256), 0, stream>>>(wc, wtc, wg, wtg, w1, wa1,
                                                       w2, w9_2, wr, w9_3,
                                                       (unsigned int*)f1t, (unsigned int*)fmt, gtmax,
                                                       img, imgb);

    conv1_iou1<<<dim3(8, 400), dim3(256), 0, stream>>>(imgb, wa1, b1, f1t, gt, aarg, gtmax);
    conv2_iou2<<<dim3(6, 100), dim3(512), 0, stream>>>(f1t, w9_2, b2, fm, fmt,
                                                       gt, gtmax, negm, posm, cands, candi, cnt);
    conv3_head<<<dim3(4, 100), dim3(512), 0, stream>>>(fmt, w9_3, br, wtc, wtg, cpart, rpart);
    tail_kernel<<<dim3(1), dim3(64), 0, stream>>>(negm, posm, cands, candi, cnt,
                                                  cpart, rpart, bc, bg, aarg, gt, gtc, out);
}